// Round 8
// baseline (623.494 us; speedup 1.0000x reference)
//
#include <hip/hip_runtime.h>
#include <math.h>

#define Bq 64
#define Lq 256
#define Eq 300
#define Hq 128
#define MQ (Bq*Lq)   // 16384

#define LRELU_S 0.2f

typedef float f32x4 __attribute__((ext_vector_type(4)));

__device__ __forceinline__ float lrelu(float x) { return x > 0.f ? x : LRELU_S * x; }

// call-free tanh: one v_exp + div, exact sign/saturation behavior
__device__ __forceinline__ float tanh_fast(float x) {
  float ax = fabsf(x);
  float e = __expf(-2.f * ax);          // (0,1], never overflows
  float r = (1.f - e) / (1.f + e);
  return copysignf(r, x);
}

// ---------------------------------------------------------------------------
// Generic tiled GEMM: C[m,n] = sum_k A[m,k]*W[n,k] (+ bias[n])
// ---------------------------------------------------------------------------
#define BM 64
#define BN 64
#define BK 16

__global__ __launch_bounds__(256) void gemm_awt(
    const float* __restrict__ Asrc, const int* __restrict__ ids,
    const float* __restrict__ W, const float* __restrict__ bias,
    float* __restrict__ C, int M, int N, int K)
{
  __shared__ float As[BK][BM + 4];
  __shared__ float Bs[BK][BN + 4];
  int tid = threadIdx.x;
  int tx = tid & 15, ty = tid >> 4;
  int row0 = blockIdx.x * BM, col0 = blockIdx.y * BN;

  int lrow = tid >> 2;          // 0..63
  int lk   = (tid & 3) << 2;    // 0,4,8,12

  const float* Arow;
  {
    int r = row0 + lrow;
    int id = ids ? ids[r] : r;
    Arow = Asrc + (size_t)id * K;
  }
  const float* Wrow = W + (size_t)(col0 + lrow) * K;

  float acc[4][4] = {};

  for (int k0 = 0; k0 < K; k0 += BK) {
    int kk = k0 + lk;
    float4 av, bv;
    if (kk + 3 < K) {
      av = *(const float4*)(Arow + kk);
      bv = *(const float4*)(Wrow + kk);
    } else {
      float a0 = (kk + 0 < K) ? Arow[kk + 0] : 0.f;
      float a1 = (kk + 1 < K) ? Arow[kk + 1] : 0.f;
      float a2 = (kk + 2 < K) ? Arow[kk + 2] : 0.f;
      float a3 = (kk + 3 < K) ? Arow[kk + 3] : 0.f;
      av = make_float4(a0, a1, a2, a3);
      float b0 = (kk + 0 < K) ? Wrow[kk + 0] : 0.f;
      float b1 = (kk + 1 < K) ? Wrow[kk + 1] : 0.f;
      float b2 = (kk + 2 < K) ? Wrow[kk + 2] : 0.f;
      float b3 = (kk + 3 < K) ? Wrow[kk + 3] : 0.f;
      bv = make_float4(b0, b1, b2, b3);
    }
    As[lk + 0][lrow] = av.x; As[lk + 1][lrow] = av.y;
    As[lk + 2][lrow] = av.z; As[lk + 3][lrow] = av.w;
    Bs[lk + 0][lrow] = bv.x; Bs[lk + 1][lrow] = bv.y;
    Bs[lk + 2][lrow] = bv.z; Bs[lk + 3][lrow] = bv.w;
    __syncthreads();

    #pragma unroll
    for (int k = 0; k < BK; ++k) {
      float4 a4 = *(const float4*)&As[k][ty * 4];
      float4 b4 = *(const float4*)&Bs[k][tx * 4];
      float a[4] = {a4.x, a4.y, a4.z, a4.w};
      float bb[4] = {b4.x, b4.y, b4.z, b4.w};
      #pragma unroll
      for (int i = 0; i < 4; ++i)
        #pragma unroll
        for (int j = 0; j < 4; ++j)
          acc[i][j] += a[i] * bb[j];
    }
    __syncthreads();
  }

  #pragma unroll
  for (int i = 0; i < 4; ++i) {
    int r = row0 + ty * 4 + i;
    #pragma unroll
    for (int j = 0; j < 4; ++j) {
      int cidx = col0 + tx * 4 + j;
      float v = acc[i][j] + (bias ? bias[cidx] : 0.f);
      C[(size_t)r * N + cidx] = v;
    }
  }
}

// ---------------------------------------------------------------------------
// Fused gates GEMM, 128x128 tile: C[m, 0:512] = emb[ids[m]] @ Wih_f^T + b_f
//                                 C[m, 512:1024] = emb[ids[m]] @ Wih_b^T + b_b
// ---------------------------------------------------------------------------
#define GBM 128
#define GBN 128
#define GBK 16

__global__ __launch_bounds__(256) void gemm_gates(
    const float* __restrict__ emb, const int* __restrict__ ids,
    const float* __restrict__ Wf, const float* __restrict__ bf,
    const float* __restrict__ Wb, const float* __restrict__ bb_,
    float* __restrict__ C)
{
  const int K = Eq;  // 300
  __shared__ float As[GBK][GBM + 4];
  __shared__ float Bs[GBK][GBN + 4];
  int tid = threadIdx.x;
  int tx = tid & 15, ty = tid >> 4;
  int row0 = blockIdx.x * GBM;
  int col0 = blockIdx.y * GBN;          // 0..896; 128 | 512 so one half per block
  const float* W    = (col0 < 512) ? Wf : Wb;
  const float* bias = (col0 < 512) ? bf : bb_;
  int wcol0 = col0 & 511;

  int lrow = tid >> 1;          // 0..127
  int lk8  = (tid & 1) << 3;    // 0 or 8

  const float* Arow = emb + (size_t)ids[row0 + lrow] * K;
  const float* Wrow = W + (size_t)(wcol0 + lrow) * K;

  float acc[2][2][4][4] = {};

  for (int k0 = 0; k0 < K; k0 += GBK) {
    #pragma unroll
    for (int half = 0; half < 2; ++half) {
      int kk = k0 + lk8 + half * 4;
      float4 av, bv;
      if (kk + 3 < K) {
        av = *(const float4*)(Arow + kk);
        bv = *(const float4*)(Wrow + kk);
      } else {
        float aa[4], bw[4];
        #pragma unroll
        for (int q = 0; q < 4; ++q) {
          aa[q] = (kk + q < K) ? Arow[kk + q] : 0.f;
          bw[q] = (kk + q < K) ? Wrow[kk + q] : 0.f;
        }
        av = make_float4(aa[0], aa[1], aa[2], aa[3]);
        bv = make_float4(bw[0], bw[1], bw[2], bw[3]);
      }
      int kb = lk8 + half * 4;
      As[kb + 0][lrow] = av.x; As[kb + 1][lrow] = av.y;
      As[kb + 2][lrow] = av.z; As[kb + 3][lrow] = av.w;
      Bs[kb + 0][lrow] = bv.x; Bs[kb + 1][lrow] = bv.y;
      Bs[kb + 2][lrow] = bv.z; Bs[kb + 3][lrow] = bv.w;
    }
    __syncthreads();

    #pragma unroll
    for (int k = 0; k < GBK; ++k) {
      float4 a0 = *(const float4*)&As[k][ty * 4];
      float4 a1 = *(const float4*)&As[k][64 + ty * 4];
      float4 b0 = *(const float4*)&Bs[k][tx * 4];
      float4 b1 = *(const float4*)&Bs[k][64 + tx * 4];
      float av_[2][4] = {{a0.x, a0.y, a0.z, a0.w}, {a1.x, a1.y, a1.z, a1.w}};
      float bv_[2][4] = {{b0.x, b0.y, b0.z, b0.w}, {b1.x, b1.y, b1.z, b1.w}};
      #pragma unroll
      for (int ra = 0; ra < 2; ++ra)
        #pragma unroll
        for (int rb = 0; rb < 2; ++rb)
          #pragma unroll
          for (int i = 0; i < 4; ++i)
            #pragma unroll
            for (int j = 0; j < 4; ++j)
              acc[ra][rb][i][j] += av_[ra][i] * bv_[rb][j];
    }
    __syncthreads();
  }

  #pragma unroll
  for (int ra = 0; ra < 2; ++ra)
    #pragma unroll
    for (int i = 0; i < 4; ++i) {
      int r = row0 + ra * 64 + ty * 4 + i;
      #pragma unroll
      for (int rb = 0; rb < 2; ++rb)
        #pragma unroll
        for (int j = 0; j < 4; ++j) {
          int cc = rb * 64 + tx * 4 + j;
          C[(size_t)r * 1024 + col0 + cc] = acc[ra][rb][i][j] + bias[wcol0 + cc];
        }
    }
}

// ---------------------------------------------------------------------------
// BiLSTM recurrence. One block per (sample, direction), 512 threads.
// Row mapping: wave w, lane l -> gate = (l>>4)&3, hidx = 16w + (l&15),
// row = gate*128 + hidx. Gate exchange via 4 __shfl, 1 barrier/step.
//
// U residency: the round-5 "+v" mega-pin failed (VGPR stuck at 76 — the
// allocator split live ranges and re-fetched 256 KB/block/step from L2, the
// measured 289 us L2-BW bound: 16 blk/XCD x 256 KB / 4.3 TB/s = 0.93 us/step).
// Fix: pin U into AGPRs ("+a" constraint). gfx950's unified reg file gives
// 512 regs/lane; AGPRs have ZERO competing pressure in this kernel, so the
// allocator has no reason to spill them. 128 a-regs + ~64 v-regs per thread
// at 2 waves/SIMD = 384/512 pool -> occupancy preserved, U traffic -> 0.
// ---------------------------------------------------------------------------
__global__ __launch_bounds__(512, 1) void lstm_kernel(
    const float* __restrict__ gates,
    const float* __restrict__ Uf, const float* __restrict__ Ub,
    float* __restrict__ h_seq)
{
  int blk = blockIdx.x;      // 0..127
  int b = blk & 63;
  int dir = blk >> 6;
  int j = threadIdx.x;       // 0..511
  int lane = j & 63;
  int w = j >> 6;            // wave 0..7
  int gate = (lane >> 4) & 3;          // 0:i 1:f 2:g 3:o
  int hidx = (w << 4) | (lane & 15);   // 0..127
  int row = (gate << 7) | hidx;        // 0..511

  const float* U = dir ? Ub : Uf;
  const f32x4* Urow = (const f32x4*)(U + (size_t)row * Hq);

#define UDECL(m) f32x4 u##m = Urow[m];
  UDECL(0)  UDECL(1)  UDECL(2)  UDECL(3)  UDECL(4)  UDECL(5)  UDECL(6)  UDECL(7)
  UDECL(8)  UDECL(9)  UDECL(10) UDECL(11) UDECL(12) UDECL(13) UDECL(14) UDECL(15)
  UDECL(16) UDECL(17) UDECL(18) UDECL(19) UDECL(20) UDECL(21) UDECL(22) UDECL(23)
  UDECL(24) UDECL(25) UDECL(26) UDECL(27) UDECL(28) UDECL(29) UDECL(30) UDECL(31)
#undef UDECL

  // AGPR mega-pin: all 32 f32x4 (=128 AGPRs) live at this point, every use
#define MEGAPIN() asm volatile("" : \
  "+a"(u0),"+a"(u1),"+a"(u2),"+a"(u3),"+a"(u4),"+a"(u5),"+a"(u6),"+a"(u7), \
  "+a"(u8),"+a"(u9),"+a"(u10),"+a"(u11),"+a"(u12),"+a"(u13),"+a"(u14),"+a"(u15), \
  "+a"(u16),"+a"(u17),"+a"(u18),"+a"(u19),"+a"(u20),"+a"(u21),"+a"(u22),"+a"(u23), \
  "+a"(u24),"+a"(u25),"+a"(u26),"+a"(u27),"+a"(u28),"+a"(u29),"+a"(u30),"+a"(u31))

  MEGAPIN();   // prologue: force U into AGPRs before the loop

  __shared__ __align__(16) float h_sh[2][Hq];
  if (j < Hq) h_sh[0][j] = 0.f;
  float c = 0.f;

  const float* gbase = gates + ((size_t)b * Lq) * 1024 + dir * 512 + row;
  int tt0 = dir ? (Lq - 1) : 0;
  float gcur = gbase[(size_t)tt0 * 1024];
  __syncthreads();

  for (int t = 0; t < Lq; ++t) {
    MEGAPIN();   // U stays in AGPRs across iterations (no memory round-trip)

    // prefetch next step's gate value (latency hidden under the fma chain)
    float gnext = 0.f;
    int tn = t + 1;
    if (tn < Lq) {
      int ttn = dir ? (Lq - 1 - tn) : tn;
      gnext = gbase[(size_t)ttn * 1024];
    }

    // cooperative h fetch: lane m holds h[2m], h[2m+1]
    float2 hp = *(const float2*)(&h_sh[t & 1][lane * 2]);
    int hx = __float_as_int(hp.x);
    int hy = __float_as_int(hp.y);

    float a0 = 0.f, a1 = 0.f, a2 = 0.f, a3 = 0.f;
#define ACC(m) { \
    a0 = fmaf(__int_as_float(__builtin_amdgcn_readlane(hx, 2*(m)  )), u##m[0], a0); \
    a1 = fmaf(__int_as_float(__builtin_amdgcn_readlane(hy, 2*(m)  )), u##m[1], a1); \
    a2 = fmaf(__int_as_float(__builtin_amdgcn_readlane(hx, 2*(m)+1)), u##m[2], a2); \
    a3 = fmaf(__int_as_float(__builtin_amdgcn_readlane(hy, 2*(m)+1)), u##m[3], a3); }
    ACC(0)  ACC(1)  ACC(2)  ACC(3)  ACC(4)  ACC(5)  ACC(6)  ACC(7)
    ACC(8)  ACC(9)  ACC(10) ACC(11) ACC(12) ACC(13) ACC(14) ACC(15)
    ACC(16) ACC(17) ACC(18) ACC(19) ACC(20) ACC(21) ACC(22) ACC(23)
    ACC(24) ACC(25) ACC(26) ACC(27) ACC(28) ACC(29) ACC(30) ACC(31)
#undef ACC

    float g = gcur + ((a0 + a2) + (a1 + a3));
    gcur = gnext;

    // branch-free nonlinearity: sigmoid for i/f/o, tanh for g. One v_exp each.
    bool isg = (gate == 2);
    float ax = fabsf(g);
    float arg = isg ? (-2.f * ax) : (-g);
    float e = __expf(arg);
    float inv = 1.f / (1.f + e);
    float r = isg ? (1.f - e) * inv : inv;
    float nl = isg ? copysignf(r, g) : r;

    // in-wave gate exchange: lanes {base, base+16, base+32, base+48} hold
    // i,f,g,o for the same hidx
    int base = lane & 15;
    float si = __shfl(nl, base,      64);
    float sf = __shfl(nl, base + 16, 64);
    float tg = __shfl(nl, base + 32, 64);
    float so = __shfl(nl, base + 48, 64);
    c = sf * c + si * tg;             // redundant across the 4 gate groups
    float h = so * tanh_fast(c);

    if (lane < 16) {
      h_sh[(t & 1) ^ 1][hidx] = h;
      int tt = dir ? (Lq - 1 - t) : t;
      h_seq[((size_t)b * Lq + tt) * 256 + dir * Hq + hidx] = h;
    }
    __syncthreads();
  }
#undef MEGAPIN
}

// ---------------------------------------------------------------------------
// GAT1 attention-score projections: s_src/s_trg[b,l,h] from proj1 [M,64]
// ---------------------------------------------------------------------------
__global__ void srctrg_kernel(const float* __restrict__ proj1,
                              const float* __restrict__ a_src,
                              const float* __restrict__ a_trg,
                              float* __restrict__ s_src, float* __restrict__ s_trg)
{
  int m = blockIdx.x * blockDim.x + threadIdx.x;
  if (m >= MQ) return;
  const float* p = proj1 + (size_t)m * 64;
  #pragma unroll
  for (int h = 0; h < 8; ++h) {
    float ss = 0.f, st = 0.f;
    #pragma unroll
    for (int f = 0; f < 8; ++f) {
      float v = p[h * 8 + f];
      ss += v * a_src[h * 8 + f];
      st += v * a_trg[h * 8 + f];
    }
    s_src[(size_t)m * 8 + h] = ss;
    s_trg[(size_t)m * 8 + h] = st;
  }
}

// ---------------------------------------------------------------------------
// GAT1 per-graph max: m1[b] = lrelu( max_h ( max_s src + max_t trg ) )
// ---------------------------------------------------------------------------
__global__ __launch_bounds__(256) void gat1max_kernel(
    const float* __restrict__ s_src, const float* __restrict__ s_trg,
    float* __restrict__ m1)
{
  int b = blockIdx.x;
  int tid = threadIdx.x;
  int h = tid >> 5, r = tid & 31;
  float ms = -3.4e38f, mt = -3.4e38f;
  for (int s = r; s < Lq; s += 32) {
    ms = fmaxf(ms, s_src[((size_t)b * Lq + s) * 8 + h]);
    mt = fmaxf(mt, s_trg[((size_t)b * Lq + s) * 8 + h]);
  }
  #pragma unroll
  for (int o = 16; o > 0; o >>= 1) {
    ms = fmaxf(ms, __shfl_xor(ms, o, 32));
    mt = fmaxf(mt, __shfl_xor(mt, o, 32));
  }
  __shared__ float hh[8];
  if (r == 0) hh[h] = ms + mt;
  __syncthreads();
  if (tid == 0) {
    float mm = -3.4e38f;
    #pragma unroll
    for (int k = 0; k < 8; ++k) mm = fmaxf(mm, hh[k]);
    m1[b] = lrelu(mm);
  }
}

// ---------------------------------------------------------------------------
// GAT1 aggregation: block per (b,h); thread per target t.
// ---------------------------------------------------------------------------
__global__ __launch_bounds__(256) void gat1_agg_kernel(
    const float* __restrict__ s_src, const float* __restrict__ s_trg,
    const float* __restrict__ proj1, const float* __restrict__ m1,
    const float* __restrict__ g1_b, float* __restrict__ h1)
{
  int b = blockIdx.x >> 3;
  int h = blockIdx.x & 7;
  int t = threadIdx.x;
  __shared__ float src_s[Lq], trg_s[Lq];
  __shared__ float proj_s[Lq * 8];

  size_t base = (size_t)b * Lq;
  src_s[t] = s_src[(base + t) * 8 + h];
  trg_s[t] = s_trg[(base + t) * 8 + h];
  {
    const float4* pr = (const float4*)(proj1 + (base + t) * 64 + h * 8);
    float4* psh = (float4*)(proj_s + t * 8);
    psh[0] = pr[0];
    psh[1] = pr[1];
  }
  __syncthreads();

  float m = m1[b];
  float mytrg = trg_s[t];
  float den = 1e-16f;
  float acc[8] = {};
  for (int s = 0; s < Lq; ++s) {
    float w = __expf(lrelu(src_s[s] + mytrg) - m);
    den += w;
    const float* ps = proj_s + s * 8;
    #pragma unroll
    for (int f = 0; f < 8; ++f) acc[f] += w * ps[f];
  }
  float inv = 1.f / den;
  float* out = h1 + (base + t) * 64 + h * 8;
  #pragma unroll
  for (int f = 0; f < 8; ++f) {
    float v = acc[f] * inv + g1_b[h * 8 + f];
    out[f] = v > 0.f ? v : expm1f(v);   // ELU
  }
}

// ---------------------------------------------------------------------------
// block reductions over 256 threads (4 waves of 64)
// ---------------------------------------------------------------------------
__device__ __forceinline__ float block_max_256(float v, volatile float* red) {
  #pragma unroll
  for (int o = 32; o > 0; o >>= 1) v = fmaxf(v, __shfl_xor(v, o, 64));
  int tid = threadIdx.x;
  if ((tid & 63) == 0) red[tid >> 6] = v;
  __syncthreads();
  float r = fmaxf(fmaxf(red[0], red[1]), fmaxf(red[2], red[3]));
  __syncthreads();
  return r;
}
__device__ __forceinline__ float block_sum_256(float v, volatile float* red) {
  #pragma unroll
  for (int o = 32; o > 0; o >>= 1) v += __shfl_xor(v, o, 64);
  int tid = threadIdx.x;
  if ((tid & 63) == 0) red[tid >> 6] = v;
  __syncthreads();
  float r = red[0] + red[1] + red[2] + red[3];
  __syncthreads();
  return r;
}

// ---------------------------------------------------------------------------
// GAT2 (1 head, 1 feat) -> att weights -> softmax -> weighted-max pooling.
// ---------------------------------------------------------------------------
__global__ __launch_bounds__(256) void gat2_att_pool_kernel(
    const float* __restrict__ h1, const float* __restrict__ g2_W,
    const float* __restrict__ g2_src, const float* __restrict__ g2_trg,
    const float* __restrict__ ctx, const float* __restrict__ h_seq,
    float* __restrict__ att_out, float* __restrict__ pooled)
{
  int b = blockIdx.x;
  int tid = threadIdx.x;
  __shared__ float w2[64];
  __shared__ float src2[Lq], trg2[Lq], dq[Lq], att_sh[Lq];
  __shared__ float red[4];

  if (tid < 64) w2[tid] = g2_W[tid];
  __syncthreads();

  const float* hr = h1 + ((size_t)b * Lq + tid) * 64;
  float p = 0.f;
  #pragma unroll
  for (int k = 0; k < 64; ++k) p += hr[k] * w2[k];
  float a_s = g2_src[0], a_t = g2_trg[0];
  src2[tid] = p * a_s;
  trg2[tid] = p * a_t;
  __syncthreads();

  float ms = block_max_256(src2[tid], red);
  float mt = block_max_256(trg2[tid], red);
  float m2 = lrelu(ms + mt);

  float mytrg = trg2[tid];
  float den = 1e-16f;
  for (int s = 0; s < Lq; ++s)
    den += __expf(lrelu(src2[s] + mytrg) - m2);
  dq[tid] = ctx[tid] / den;
  __syncthreads();

  float mysrc = src2[tid];
  float raw = 0.f;
  for (int t = 0; t < Lq; ++t)
    raw += dq[t] * __expf(lrelu(mysrc + trg2[t]) - m2);

  float mr = block_max_256(raw, red);
  float e = __expf(raw - mr);
  float ssum = block_sum_256(e, red);
  float att = e / ssum;
  att_out[(size_t)b * Lq + tid] = att;
  att_sh[tid] = att;
  __syncthreads();

  float pm = -3.4e38f;
  for (int l = 0; l < Lq; ++l)
    pm = fmaxf(pm, h_seq[((size_t)b * Lq + l) * 256 + tid] * att_sh[l]);
  pooled[(size_t)b * 256 + tid] = pm;
}

// ---------------------------------------------------------------------------
// Head: grid(64) — one block per sample.
// ---------------------------------------------------------------------------
__global__ __launch_bounds__(256) void head_kernel(
    const float* __restrict__ pooled, const float* __restrict__ lin_W,
    const float* __restrict__ lin_b, const float* __restrict__ out_W,
    const float* __restrict__ out_b, float* __restrict__ logits)
{
  int i = blockIdx.x;
  int tid = threadIdx.x;
  int j = tid & 63, kq = tid >> 6;   // 4 k-chunks of 64
  __shared__ float part[4][64];
  __shared__ float hcl[64];
  const float* pr = pooled + i * 256 + kq * 64;
  const float* wr = lin_W + j * 256 + kq * 64;
  float d = 0.f;
  #pragma unroll
  for (int k = 0; k < 64; ++k) d += pr[k] * wr[k];
  part[kq][j] = d;
  __syncthreads();
  if (tid < 64) {
    float v = part[0][j] + part[1][j] + part[2][j] + part[3][j] + lin_b[j];
    hcl[j] = fmaxf(v, 0.f);
  }
  __syncthreads();
  if (tid < 128) {
    int cc = tid >> 6, jj = tid & 63;
    float p = hcl[jj] * out_W[cc * 64 + jj];
    #pragma unroll
    for (int o = 32; o > 0; o >>= 1) p += __shfl_xor(p, o, 64);
    if (jj == 0) logits[i * 2 + cc] = p + out_b[cc];
  }
}

// ---------------------------------------------------------------------------
extern "C" void kernel_launch(void* const* d_in, const int* in_sizes, int n_in,
                              void* d_out, int out_size, void* d_ws, size_t ws_size,
                              hipStream_t stream)
{
  const int*   ids    = (const int*)  d_in[0];
  // d_in[1] = attention_mask (all ones by construction; unused)
  const float* emb    = (const float*)d_in[2];
  const float* Wih_f  = (const float*)d_in[3];
  const float* Whh_f  = (const float*)d_in[4];
  const float* b_f    = (const float*)d_in[5];
  const float* Wih_b  = (const float*)d_in[6];
  const float* Whh_b  = (const float*)d_in[7];
  const float* b_b    = (const float*)d_in[8];
  const float* g1_W   = (const float*)d_in[9];
  const float* g1_src = (const float*)d_in[10];
  const float* g1_trg = (const float*)d_in[11];
  const float* g1_b   = (const float*)d_in[12];
  const float* g2_W   = (const float*)d_in[13];
  const float* g2_src = (const float*)d_in[14];
  const float* g2_trg = (const float*)d_in[15];
  // d_in[16] = g2_b (unused)
  const float* ctx    = (const float*)d_in[17];
  const float* lin_W  = (const float*)d_in[18];
  const float* lin_b  = (const float*)d_in[19];
  const float* out_W  = (const float*)d_in[20];
  const float* out_b  = (const float*)d_in[21];

  float* out_f   = (float*)d_out;
  float* logits  = out_f;          // [64,2]
  float* att_out = out_f + 128;    // [64,256]

  float* ws = (float*)d_ws;
  const size_t M = MQ;
  float* gates   = ws; ws += M * 1024;   // [M][1024] fwd|bwd
  float* h_seq   = ws; ws += M * 256;
  float* proj1   = ws; ws += M * 64;
  float* s_src   = ws; ws += M * 8;
  float* s_trg   = ws; ws += M * 8;
  float* h1      = ws; ws += M * 64;
  float* m1      = ws; ws += 64;
  float* pooled  = ws; ws += 64 * 256;

  dim3 thr(256);

  // Stage A: fused embedding-gather + both input-gate GEMMs (K=300, N=1024)
  gemm_gates<<<dim3(MQ / GBM, 1024 / GBN), thr, 0, stream>>>(emb, ids, Wih_f, b_f, Wih_b, b_b, gates);

  // Stage B: BiLSTM recurrence (U pinned in AGPRs)
  lstm_kernel<<<128, 512, 0, stream>>>(gates, Whh_f, Whh_b, h_seq);

  // Stage C: GAT layer 1
  gemm_awt<<<dim3(MQ / BM, 1), thr, 0, stream>>>(h_seq, nullptr, g1_W, nullptr, proj1, MQ, 64, 256);
  srctrg_kernel<<<MQ / 256, thr, 0, stream>>>(proj1, g1_src, g1_trg, s_src, s_trg);
  gat1max_kernel<<<Bq, thr, 0, stream>>>(s_src, s_trg, m1);
  gat1_agg_kernel<<<Bq * 8, thr, 0, stream>>>(s_src, s_trg, proj1, m1, g1_b, h1);

  // Stage D: GAT layer 2 attention -> context attention -> softmax -> pooling
  gat2_att_pool_kernel<<<Bq, thr, 0, stream>>>(h1, g2_W, g2_src, g2_trg, ctx, h_seq, att_out, pooled);

  // Stage E: classifier head
  head_kernel<<<64, thr, 0, stream>>>(pooled, lin_W, lin_b, out_W, out_b, logits);
}

// Round 9
// 543.023 us; speedup vs baseline: 1.1482x; 1.1482x over previous
//
#include <hip/hip_runtime.h>
#include <math.h>
#include <stdint.h>

#define Bq 64
#define Lq 256
#define Eq 300
#define Hq 128
#define MQ (Bq*Lq)   // 16384

#define LRELU_S 0.2f

__device__ __forceinline__ float lrelu(float x) { return x > 0.f ? x : LRELU_S * x; }

// ---------------------------------------------------------------------------
// Generic tiled GEMM: C[m,n] = sum_k A[m,k]*W[n,k] (+ bias[n])
// ---------------------------------------------------------------------------
#define BM 64
#define BN 64
#define BK 16

__global__ __launch_bounds__(256) void gemm_awt(
    const float* __restrict__ Asrc, const int* __restrict__ ids,
    const float* __restrict__ W, const float* __restrict__ bias,
    float* __restrict__ C, int M, int N, int K)
{
  __shared__ float As[BK][BM + 4];
  __shared__ float Bs[BK][BN + 4];
  int tid = threadIdx.x;
  int tx = tid & 15, ty = tid >> 4;
  int row0 = blockIdx.x * BM, col0 = blockIdx.y * BN;

  int lrow = tid >> 2;          // 0..63
  int lk   = (tid & 3) << 2;    // 0,4,8,12

  const float* Arow;
  {
    int r = row0 + lrow;
    int id = ids ? ids[r] : r;
    Arow = Asrc + (size_t)id * K;
  }
  const float* Wrow = W + (size_t)(col0 + lrow) * K;

  float acc[4][4] = {};

  for (int k0 = 0; k0 < K; k0 += BK) {
    int kk = k0 + lk;
    float4 av, bv;
    if (kk + 3 < K) {
      av = *(const float4*)(Arow + kk);
      bv = *(const float4*)(Wrow + kk);
    } else {
      float a0 = (kk + 0 < K) ? Arow[kk + 0] : 0.f;
      float a1 = (kk + 1 < K) ? Arow[kk + 1] : 0.f;
      float a2 = (kk + 2 < K) ? Arow[kk + 2] : 0.f;
      float a3 = (kk + 3 < K) ? Arow[kk + 3] : 0.f;
      av = make_float4(a0, a1, a2, a3);
      float b0 = (kk + 0 < K) ? Wrow[kk + 0] : 0.f;
      float b1 = (kk + 1 < K) ? Wrow[kk + 1] : 0.f;
      float b2 = (kk + 2 < K) ? Wrow[kk + 2] : 0.f;
      float b3 = (kk + 3 < K) ? Wrow[kk + 3] : 0.f;
      bv = make_float4(b0, b1, b2, b3);
    }
    As[lk + 0][lrow] = av.x; As[lk + 1][lrow] = av.y;
    As[lk + 2][lrow] = av.z; As[lk + 3][lrow] = av.w;
    Bs[lk + 0][lrow] = bv.x; Bs[lk + 1][lrow] = bv.y;
    Bs[lk + 2][lrow] = bv.z; Bs[lk + 3][lrow] = bv.w;
    __syncthreads();

    #pragma unroll
    for (int k = 0; k < BK; ++k) {
      float4 a4 = *(const float4*)&As[k][ty * 4];
      float4 b4 = *(const float4*)&Bs[k][tx * 4];
      float a[4] = {a4.x, a4.y, a4.z, a4.w};
      float bb[4] = {b4.x, b4.y, b4.z, b4.w};
      #pragma unroll
      for (int i = 0; i < 4; ++i)
        #pragma unroll
        for (int j = 0; j < 4; ++j)
          acc[i][j] += a[i] * bb[j];
    }
    __syncthreads();
  }

  #pragma unroll
  for (int i = 0; i < 4; ++i) {
    int r = row0 + ty * 4 + i;
    #pragma unroll
    for (int j = 0; j < 4; ++j) {
      int cidx = col0 + tx * 4 + j;
      float v = acc[i][j] + (bias ? bias[cidx] : 0.f);
      C[(size_t)r * N + cidx] = v;
    }
  }
}

// ---------------------------------------------------------------------------
// Fused gates GEMM, 128x128 tile: C[m, 0:512] = emb[ids[m]] @ Wih_f^T + b_f
//                                 C[m, 512:1024] = emb[ids[m]] @ Wih_b^T + b_b
// ---------------------------------------------------------------------------
#define GBM 128
#define GBN 128
#define GBK 16

__global__ __launch_bounds__(256) void gemm_gates(
    const float* __restrict__ emb, const int* __restrict__ ids,
    const float* __restrict__ Wf, const float* __restrict__ bf,
    const float* __restrict__ Wb, const float* __restrict__ bb_,
    float* __restrict__ C)
{
  const int K = Eq;  // 300
  __shared__ float As[GBK][GBM + 4];
  __shared__ float Bs[GBK][GBN + 4];
  int tid = threadIdx.x;
  int tx = tid & 15, ty = tid >> 4;
  int row0 = blockIdx.x * GBM;
  int col0 = blockIdx.y * GBN;
  const float* W    = (col0 < 512) ? Wf : Wb;
  const float* bias = (col0 < 512) ? bf : bb_;
  int wcol0 = col0 & 511;

  int lrow = tid >> 1;
  int lk8  = (tid & 1) << 3;

  const float* Arow = emb + (size_t)ids[row0 + lrow] * K;
  const float* Wrow = W + (size_t)(wcol0 + lrow) * K;

  float acc[2][2][4][4] = {};

  for (int k0 = 0; k0 < K; k0 += GBK) {
    #pragma unroll
    for (int half = 0; half < 2; ++half) {
      int kk = k0 + lk8 + half * 4;
      float4 av, bv;
      if (kk + 3 < K) {
        av = *(const float4*)(Arow + kk);
        bv = *(const float4*)(Wrow + kk);
      } else {
        float aa[4], bw[4];
        #pragma unroll
        for (int q = 0; q < 4; ++q) {
          aa[q] = (kk + q < K) ? Arow[kk + q] : 0.f;
          bw[q] = (kk + q < K) ? Wrow[kk + q] : 0.f;
        }
        av = make_float4(aa[0], aa[1], aa[2], aa[3]);
        bv = make_float4(bw[0], bw[1], bw[2], bw[3]);
      }
      int kb = lk8 + half * 4;
      As[kb + 0][lrow] = av.x; As[kb + 1][lrow] = av.y;
      As[kb + 2][lrow] = av.z; As[kb + 3][lrow] = av.w;
      Bs[kb + 0][lrow] = bv.x; Bs[kb + 1][lrow] = bv.y;
      Bs[kb + 2][lrow] = bv.z; Bs[kb + 3][lrow] = bv.w;
    }
    __syncthreads();

    #pragma unroll
    for (int k = 0; k < GBK; ++k) {
      float4 a0 = *(const float4*)&As[k][ty * 4];
      float4 a1 = *(const float4*)&As[k][64 + ty * 4];
      float4 b0 = *(const float4*)&Bs[k][tx * 4];
      float4 b1 = *(const float4*)&Bs[k][64 + tx * 4];
      float av_[2][4] = {{a0.x, a0.y, a0.z, a0.w}, {a1.x, a1.y, a1.z, a1.w}};
      float bv_[2][4] = {{b0.x, b0.y, b0.z, b0.w}, {b1.x, b1.y, b1.z, b1.w}};
      #pragma unroll
      for (int ra = 0; ra < 2; ++ra)
        #pragma unroll
        for (int rb = 0; rb < 2; ++rb)
          #pragma unroll
          for (int i = 0; i < 4; ++i)
            #pragma unroll
            for (int j = 0; j < 4; ++j)
              acc[ra][rb][i][j] += av_[ra][i] * bv_[rb][j];
    }
    __syncthreads();
  }

  #pragma unroll
  for (int ra = 0; ra < 2; ++ra)
    #pragma unroll
    for (int i = 0; i < 4; ++i) {
      int r = row0 + ra * 64 + ty * 4 + i;
      #pragma unroll
      for (int rb = 0; rb < 2; ++rb)
        #pragma unroll
        for (int j = 0; j < 4; ++j) {
          int cc = rb * 64 + tx * 4 + j;
          C[(size_t)r * 1024 + col0 + cc] = acc[ra][rb][i][j] + bias[wcol0 + cc];
        }
    }
}

// ---------------------------------------------------------------------------
// BiLSTM recurrence — FULL INLINE-ASM LOOP.
// 7 source-level attempts (r1-r7) could not make LLVM keep the 128-float U
// row resident (it remats the loads -> 256 KB/block/step from L2 = the
// ~2200 cyc/step bound; LDS is no better: 256 KB/step / 128 B/cyc = 2048).
// Here the ENTIRE 256-step loop is one asm block with hard registers:
//   v128-v255: U row (32x global_load_dwordx4, loaded once)
//   v90-v121:  temps/addresses, s90-s94: readlane temps + counter
// No compiler code runs between uses, so the clobber-register trick is sound.
// Mapping (proven in r5): wave w, lane l: gate=(l>>4)&3, hidx=16w+(l&15),
// row=gate*128+hidx. h pair per lane via ds_read_b64; broadcast via
// v_readlane; gate exchange via 4 ds_bpermute; c/h computed redundantly in
// all 4 gate-lane groups (same value -> duplicate same-address stores OK).
// sigmoid(x)=rcp(1+exp2(-x*log2e)) (+1 NR); tanh(x)=2*sigmoid(2x)-1.
// Gate stream addressed as 32-bit offset + SGPR base (no carries); gates
// buffer padded by 1024 floats in front so the t=256 prefetch of the bwd
// direction stays inside d_ws.
// ---------------------------------------------------------------------------
#define MVQ(l0,l1,r0,r1,r2,r3) \
  "v_readlane_b32 s90, v100, " #l0 "\n" \
  "v_readlane_b32 s91, v101, " #l0 "\n" \
  "v_readlane_b32 s92, v100, " #l1 "\n" \
  "v_readlane_b32 s93, v101, " #l1 "\n" \
  "v_fmac_f32 v104, s90, v" #r0 "\n" \
  "v_fmac_f32 v105, s91, v" #r1 "\n" \
  "v_fmac_f32 v106, s92, v" #r2 "\n" \
  "v_fmac_f32 v107, s93, v" #r3 "\n"

#define ULD(lo,hi,off) \
  "global_load_dwordx4 v[" #lo ":" #hi "], v90, %[ub] offset:" #off "\n"

__global__ __launch_bounds__(512, 1) void lstm_kernel(
    const float* __restrict__ ws_base,   // d_ws base; gates start at +1024 floats
    const float* __restrict__ Uf, const float* __restrict__ Ub,
    float* __restrict__ h_seq)
{
  __shared__ __align__(1024) float h_sh[2][Hq];
  int blk = blockIdx.x;      // 0..127
  int b = blk & 63;
  int dir = blk >> 6;
  int j = threadIdx.x;       // 0..511
  int lane = j & 63;
  int w = j >> 6;
  int gate = (lane >> 4) & 3;          // 0:i 1:f 2:g 3:o
  int hidx = (w << 4) | (lane & 15);   // 0..127
  int row = (gate << 7) | hidx;        // 0..511

  const float* U = dir ? Ub : Uf;
  int tt0 = dir ? (Lq - 1) : 0;

  unsigned uo  = (unsigned)row * (Hq * 4u);                     // byte off into U
  unsigned go0 = (1024u + (unsigned)(b * Lq + tt0) * 1024u
                  + (unsigned)dir * 512u + (unsigned)row) * 4u; // byte off from ws
  unsigned ho0 = ((unsigned)(b * Lq + tt0) * 256u
                  + (unsigned)dir * (unsigned)Hq + (unsigned)hidx) * 4u;
  int gd = dir ? -4096 : 4096;   // bytes per step in gates
  int hd = dir ? -1024 : 1024;   // bytes per step in h_seq

  unsigned lds_base = (unsigned)(uintptr_t)&h_sh[0][0];  // LDS aperture low32 = offset
  unsigned ldsr0 = lds_base + (unsigned)lane * 8u;       // read buf0
  unsigned ldsw0 = lds_base + 512u + (unsigned)hidx * 4u;// write buf1

  bool isg = (gate == 2);
  float klog = isg ? -2.8853900817779268f : -1.4426950408889634f; // -k*log2(e)
  float mc = isg ? 2.f : 1.f;
  float ac = isg ? -1.f : 0.f;
  int base4 = (lane & 15) * 4;
  int bp0 = base4, bp1 = base4 + 64, bp2 = base4 + 128, bp3 = base4 + 192;

  if (j < Hq) h_sh[0][j] = 0.f;
  __syncthreads();

  asm volatile(
    // ---- prologue: hard-reg setup + U load (once) + first gate ----
    "v_mov_b32 v90, %[uo]\n"
    "v_mov_b32 v94, %[ldsr0]\n"
    "v_mov_b32 v95, %[ldsw0]\n"
    "v_mov_b32 v96, %[go0]\n"
    "v_mov_b32 v97, %[ho0]\n"
    "v_mov_b32 v119, 0\n"              // c = 0
    "s_mov_b32 s94, 0\n"               // t = 0
    ULD(128,131,0)   ULD(132,135,16)  ULD(136,139,32)  ULD(140,143,48)
    ULD(144,147,64)  ULD(148,151,80)  ULD(152,155,96)  ULD(156,159,112)
    ULD(160,163,128) ULD(164,167,144) ULD(168,171,160) ULD(172,175,176)
    ULD(176,179,192) ULD(180,183,208) ULD(184,187,224) ULD(188,191,240)
    ULD(192,195,256) ULD(196,199,272) ULD(200,203,288) ULD(204,207,304)
    ULD(208,211,320) ULD(212,215,336) ULD(216,219,352) ULD(220,223,368)
    ULD(224,227,384) ULD(228,231,400) ULD(232,235,416) ULD(236,239,432)
    ULD(240,243,448) ULD(244,247,464) ULD(248,251,480) ULD(252,255,496)
    "global_load_dword v102, v96, %[wsb]\n"   // gcur (t=0)
    "s_waitcnt vmcnt(0)\n"
    // ---- time loop ----
    "Ltop_%=:\n"
    "v_add_u32 v96, %[gd], v96\n"
    "global_load_dword v103, v96, %[wsb]\n"   // prefetch gate t+1
    "ds_read_b64 v[100:101], v94\n"           // h[2l], h[2l+1]
    "v_mov_b32 v104, v102\n"                  // acc0 starts at gate input
    "v_mov_b32 v105, 0\n"
    "v_mov_b32 v106, 0\n"
    "v_mov_b32 v107, 0\n"
    "s_waitcnt lgkmcnt(0)\n"
    MVQ(0,1,128,129,130,131)   MVQ(2,3,132,133,134,135)
    MVQ(4,5,136,137,138,139)   MVQ(6,7,140,141,142,143)
    MVQ(8,9,144,145,146,147)   MVQ(10,11,148,149,150,151)
    MVQ(12,13,152,153,154,155) MVQ(14,15,156,157,158,159)
    MVQ(16,17,160,161,162,163) MVQ(18,19,164,165,166,167)
    MVQ(20,21,168,169,170,171) MVQ(22,23,172,173,174,175)
    MVQ(24,25,176,177,178,179) MVQ(26,27,180,181,182,183)
    MVQ(28,29,184,185,186,187) MVQ(30,31,188,189,190,191)
    MVQ(32,33,192,193,194,195) MVQ(34,35,196,197,198,199)
    MVQ(36,37,200,201,202,203) MVQ(38,39,204,205,206,207)
    MVQ(40,41,208,209,210,211) MVQ(42,43,212,213,214,215)
    MVQ(44,45,216,217,218,219) MVQ(46,47,220,221,222,223)
    MVQ(48,49,224,225,226,227) MVQ(50,51,228,229,230,231)
    MVQ(52,53,232,233,234,235) MVQ(54,55,236,237,238,239)
    MVQ(56,57,240,241,242,243) MVQ(58,59,244,245,246,247)
    MVQ(60,61,248,249,250,251) MVQ(62,63,252,253,254,255)
    "v_add_f32 v108, v104, v106\n"
    "v_add_f32 v121, v105, v107\n"
    "v_add_f32 v108, v108, v121\n"            // g
    // nl = mc * sigmoid(k*g) + ac
    "v_mul_f32 v109, %[klog], v108\n"
    "v_exp_f32 v110, v109\n"
    "s_nop 1\n"
    "v_add_f32 v111, 1.0, v110\n"
    "v_rcp_f32 v112, v111\n"
    "s_nop 1\n"
    "v_mul_f32 v121, v111, v112\n"            // d*r1
    "v_sub_f32 v121, 2.0, v121\n"
    "v_mul_f32 v112, v112, v121\n"            // refined rcp
    "v_fma_f32 v114, v112, %[mc], %[ac]\n"    // nl
    // gate exchange: i,f,g,o of my hidx from lanes base,+16,+32,+48
    "ds_bpermute_b32 v115, %[bp0], v114\n"
    "ds_bpermute_b32 v116, %[bp1], v114\n"
    "ds_bpermute_b32 v117, %[bp2], v114\n"
    "ds_bpermute_b32 v118, %[bp3], v114\n"
    "s_waitcnt lgkmcnt(0)\n"
    "v_mul_f32 v121, v115, v117\n"            // si*tg
    "v_fma_f32 v119, v116, v119, v121\n"      // c = sf*c + si*tg
    // h = so * tanh(c);  tanh(c) = 2*sigmoid(2c)-1
    "v_mul_f32 v109, 0xc038aa3b, v119\n"      // -2*log2e * c
    "v_exp_f32 v110, v109\n"
    "s_nop 1\n"
    "v_add_f32 v111, 1.0, v110\n"
    "v_rcp_f32 v112, v111\n"
    "s_nop 1\n"
    "v_mul_f32 v121, v111, v112\n"
    "v_sub_f32 v121, 2.0, v121\n"
    "v_mul_f32 v112, v112, v121\n"
    "v_fma_f32 v120, v112, 2.0, -1.0\n"       // tanh(c)
    "v_mul_f32 v120, v118, v120\n"            // h = so * tanh(c)
    // roll prefetched gate (prefetch issued ~280 instrs ago; old store done)
    "s_waitcnt vmcnt(0)\n"
    "v_mov_b32 v102, v103\n"
    // store h (4 gate-group lanes store same value to same addr: benign)
    "ds_write_b32 v95, v120\n"
    "global_store_dword v97, v120, %[hsb]\n"
    "v_add_u32 v97, %[hd], v97\n"
    "v_xor_b32 v94, 0x200, v94\n"             // toggle LDS read buffer
    "v_xor_b32 v95, 0x200, v95\n"             // toggle LDS write buffer
    "s_waitcnt lgkmcnt(0)\n"
    "s_barrier\n"
    "s_add_u32 s94, s94, 1\n"
    "s_cmp_lt_u32 s94, 256\n"
    "s_cbranch_scc1 Ltop_%=\n"
    "s_waitcnt vmcnt(0) lgkmcnt(0)\n"
    :
    : [wsb]"s"(ws_base), [hsb]"s"(h_seq), [ub]"s"(U),
      [gd]"s"(gd), [hd]"s"(hd),
      [uo]"v"(uo), [go0]"v"(go0), [ho0]"v"(ho0),
      [ldsr0]"v"(ldsr0), [ldsw0]"v"(ldsw0),
      [klog]"v"(klog), [mc]"v"(mc), [ac]"v"(ac),
      [bp0]"v"(bp0), [bp1]"v"(bp1), [bp2]"v"(bp2), [bp3]"v"(bp3)
    : "memory", "scc", "s90","s91","s92","s93","s94",
      "v90","v94","v95","v96","v97",
      "v100","v101","v102","v103","v104","v105","v106","v107",
      "v108","v109","v110","v111","v112","v113","v114","v115",
      "v116","v117","v118","v119","v120","v121",
      "v128","v129","v130","v131","v132","v133","v134","v135",
      "v136","v137","v138","v139","v140","v141","v142","v143",
      "v144","v145","v146","v147","v148","v149","v150","v151",
      "v152","v153","v154","v155","v156","v157","v158","v159",
      "v160","v161","v162","v163","v164","v165","v166","v167",
      "v168","v169","v170","v171","v172","v173","v174","v175",
      "v176","v177","v178","v179","v180","v181","v182","v183",
      "v184","v185","v186","v187","v188","v189","v190","v191",
      "v192","v193","v194","v195","v196","v197","v198","v199",
      "v200","v201","v202","v203","v204","v205","v206","v207",
      "v208","v209","v210","v211","v212","v213","v214","v215",
      "v216","v217","v218","v219","v220","v221","v222","v223",
      "v224","v225","v226","v227","v228","v229","v230","v231",
      "v232","v233","v234","v235","v236","v237","v238","v239",
      "v240","v241","v242","v243","v244","v245","v246","v247",
      "v248","v249","v250","v251","v252","v253","v254","v255");
}
#undef MVQ
#undef ULD

// ---------------------------------------------------------------------------
// GAT1 attention-score projections: s_src/s_trg[b,l,h] from proj1 [M,64]
// ---------------------------------------------------------------------------
__global__ void srctrg_kernel(const float* __restrict__ proj1,
                              const float* __restrict__ a_src,
                              const float* __restrict__ a_trg,
                              float* __restrict__ s_src, float* __restrict__ s_trg)
{
  int m = blockIdx.x * blockDim.x + threadIdx.x;
  if (m >= MQ) return;
  const float* p = proj1 + (size_t)m * 64;
  #pragma unroll
  for (int h = 0; h < 8; ++h) {
    float ss = 0.f, st = 0.f;
    #pragma unroll
    for (int f = 0; f < 8; ++f) {
      float v = p[h * 8 + f];
      ss += v * a_src[h * 8 + f];
      st += v * a_trg[h * 8 + f];
    }
    s_src[(size_t)m * 8 + h] = ss;
    s_trg[(size_t)m * 8 + h] = st;
  }
}

// ---------------------------------------------------------------------------
// GAT1 per-graph max: m1[b] = lrelu( max_h ( max_s src + max_t trg ) )
// ---------------------------------------------------------------------------
__global__ __launch_bounds__(256) void gat1max_kernel(
    const float* __restrict__ s_src, const float* __restrict__ s_trg,
    float* __restrict__ m1)
{
  int b = blockIdx.x;
  int tid = threadIdx.x;
  int h = tid >> 5, r = tid & 31;
  float ms = -3.4e38f, mt = -3.4e38f;
  for (int s = r; s < Lq; s += 32) {
    ms = fmaxf(ms, s_src[((size_t)b * Lq + s) * 8 + h]);
    mt = fmaxf(mt, s_trg[((size_t)b * Lq + s) * 8 + h]);
  }
  #pragma unroll
  for (int o = 16; o > 0; o >>= 1) {
    ms = fmaxf(ms, __shfl_xor(ms, o, 32));
    mt = fmaxf(mt, __shfl_xor(mt, o, 32));
  }
  __shared__ float hh[8];
  if (r == 0) hh[h] = ms + mt;
  __syncthreads();
  if (tid == 0) {
    float mm = -3.4e38f;
    #pragma unroll
    for (int k = 0; k < 8; ++k) mm = fmaxf(mm, hh[k]);
    m1[b] = lrelu(mm);
  }
}

// ---------------------------------------------------------------------------
// GAT1 aggregation: block per (b,h); thread per target t.
// ---------------------------------------------------------------------------
__global__ __launch_bounds__(256) void gat1_agg_kernel(
    const float* __restrict__ s_src, const float* __restrict__ s_trg,
    const float* __restrict__ proj1, const float* __restrict__ m1,
    const float* __restrict__ g1_b, float* __restrict__ h1)
{
  int b = blockIdx.x >> 3;
  int h = blockIdx.x & 7;
  int t = threadIdx.x;
  __shared__ float src_s[Lq], trg_s[Lq];
  __shared__ float proj_s[Lq * 8];

  size_t base = (size_t)b * Lq;
  src_s[t] = s_src[(base + t) * 8 + h];
  trg_s[t] = s_trg[(base + t) * 8 + h];
  {
    const float4* pr = (const float4*)(proj1 + (base + t) * 64 + h * 8);
    float4* psh = (float4*)(proj_s + t * 8);
    psh[0] = pr[0];
    psh[1] = pr[1];
  }
  __syncthreads();

  float m = m1[b];
  float mytrg = trg_s[t];
  float den = 1e-16f;
  float acc[8] = {};
  for (int s = 0; s < Lq; ++s) {
    float w = __expf(lrelu(src_s[s] + mytrg) - m);
    den += w;
    const float* ps = proj_s + s * 8;
    #pragma unroll
    for (int f = 0; f < 8; ++f) acc[f] += w * ps[f];
  }
  float inv = 1.f / den;
  float* out = h1 + (base + t) * 64 + h * 8;
  #pragma unroll
  for (int f = 0; f < 8; ++f) {
    float v = acc[f] * inv + g1_b[h * 8 + f];
    out[f] = v > 0.f ? v : expm1f(v);   // ELU
  }
}

// ---------------------------------------------------------------------------
// block reductions over 256 threads (4 waves of 64)
// ---------------------------------------------------------------------------
__device__ __forceinline__ float block_max_256(float v, volatile float* red) {
  #pragma unroll
  for (int o = 32; o > 0; o >>= 1) v = fmaxf(v, __shfl_xor(v, o, 64));
  int tid = threadIdx.x;
  if ((tid & 63) == 0) red[tid >> 6] = v;
  __syncthreads();
  float r = fmaxf(fmaxf(red[0], red[1]), fmaxf(red[2], red[3]));
  __syncthreads();
  return r;
}
__device__ __forceinline__ float block_sum_256(float v, volatile float* red) {
  #pragma unroll
  for (int o = 32; o > 0; o >>= 1) v += __shfl_xor(v, o, 64);
  int tid = threadIdx.x;
  if ((tid & 63) == 0) red[tid >> 6] = v;
  __syncthreads();
  float r = red[0] + red[1] + red[2] + red[3];
  __syncthreads();
  return r;
}

// ---------------------------------------------------------------------------
// GAT2 (1 head, 1 feat) -> att weights -> softmax -> weighted-max pooling.
// ---------------------------------------------------------------------------
__global__ __launch_bounds__(256) void gat2_att_pool_kernel(
    const float* __restrict__ h1, const float* __restrict__ g2_W,
    const float* __restrict__ g2_src, const float* __restrict__ g2_trg,
    const float* __restrict__ ctx, const float* __restrict__ h_seq,
    float* __restrict__ att_out, float* __restrict__ pooled)
{
  int b = blockIdx.x;
  int tid = threadIdx.x;
  __shared__ float w2[64];
  __shared__ float src2[Lq], trg2[Lq], dq[Lq], att_sh[Lq];
  __shared__ float red[4];

  if (tid < 64) w2[tid] = g2_W[tid];
  __syncthreads();

  const float* hr = h1 + ((size_t)b * Lq + tid) * 64;
  float p = 0.f;
  #pragma unroll
  for (int k = 0; k < 64; ++k) p += hr[k] * w2[k];
  float a_s = g2_src[0], a_t = g2_trg[0];
  src2[tid] = p * a_s;
  trg2[tid] = p * a_t;
  __syncthreads();

  float ms = block_max_256(src2[tid], red);
  float mt = block_max_256(trg2[tid], red);
  float m2 = lrelu(ms + mt);

  float mytrg = trg2[tid];
  float den = 1e-16f;
  for (int s = 0; s < Lq; ++s)
    den += __expf(lrelu(src2[s] + mytrg) - m2);
  dq[tid] = ctx[tid] / den;
  __syncthreads();

  float mysrc = src2[tid];
  float raw = 0.f;
  for (int t = 0; t < Lq; ++t)
    raw += dq[t] * __expf(lrelu(mysrc + trg2[t]) - m2);

  float mr = block_max_256(raw, red);
  float e = __expf(raw - mr);
  float ssum = block_sum_256(e, red);
  float att = e / ssum;
  att_out[(size_t)b * Lq + tid] = att;
  att_sh[tid] = att;
  __syncthreads();

  float pm = -3.4e38f;
  for (int l = 0; l < Lq; ++l)
    pm = fmaxf(pm, h_seq[((size_t)b * Lq + l) * 256 + tid] * att_sh[l]);
  pooled[(size_t)b * 256 + tid] = pm;
}

// ---------------------------------------------------------------------------
// Head: grid(64) — one block per sample.
// ---------------------------------------------------------------------------
__global__ __launch_bounds__(256) void head_kernel(
    const float* __restrict__ pooled, const float* __restrict__ lin_W,
    const float* __restrict__ lin_b, const float* __restrict__ out_W,
    const float* __restrict__ out_b, float* __restrict__ logits)
{
  int i = blockIdx.x;
  int tid = threadIdx.x;
  int j = tid & 63, kq = tid >> 6;
  __shared__ float part[4][64];
  __shared__ float hcl[64];
  const float* pr = pooled + i * 256 + kq * 64;
  const float* wr = lin_W + j * 256 + kq * 64;
  float d = 0.f;
  #pragma unroll
  for (int k = 0; k < 64; ++k) d += pr[k] * wr[k];
  part[kq][j] = d;
  __syncthreads();
  if (tid < 64) {
    float v = part[0][j] + part[1][j] + part[2][j] + part[3][j] + lin_b[j];
    hcl[j] = fmaxf(v, 0.f);
  }
  __syncthreads();
  if (tid < 128) {
    int cc = tid >> 6, jj = tid & 63;
    float p = hcl[jj] * out_W[cc * 64 + jj];
    #pragma unroll
    for (int o = 32; o > 0; o >>= 1) p += __shfl_xor(p, o, 64);
    if (jj == 0) logits[i * 2 + cc] = p + out_b[cc];
  }
}

// ---------------------------------------------------------------------------
extern "C" void kernel_launch(void* const* d_in, const int* in_sizes, int n_in,
                              void* d_out, int out_size, void* d_ws, size_t ws_size,
                              hipStream_t stream)
{
  const int*   ids    = (const int*)  d_in[0];
  // d_in[1] = attention_mask (all ones by construction; unused)
  const float* emb    = (const float*)d_in[2];
  const float* Wih_f  = (const float*)d_in[3];
  const float* Whh_f  = (const float*)d_in[4];
  const float* b_f    = (const float*)d_in[5];
  const float* Wih_b  = (const float*)d_in[6];
  const float* Whh_b  = (const float*)d_in[7];
  const float* b_b    = (const float*)d_in[8];
  const float* g1_W   = (const float*)d_in[9];
  const float* g1_src = (const float*)d_in[10];
  const float* g1_trg = (const float*)d_in[11];
  const float* g1_b   = (const float*)d_in[12];
  const float* g2_W   = (const float*)d_in[13];
  const float* g2_src = (const float*)d_in[14];
  const float* g2_trg = (const float*)d_in[15];
  // d_in[16] = g2_b (unused)
  const float* ctx    = (const float*)d_in[17];
  const float* lin_W  = (const float*)d_in[18];
  const float* lin_b  = (const float*)d_in[19];
  const float* out_W  = (const float*)d_in[20];
  const float* out_b  = (const float*)d_in[21];

  float* out_f   = (float*)d_out;
  float* logits  = out_f;          // [64,2]
  float* att_out = out_f + 128;    // [64,256]

  float* ws = (float*)d_ws;
  const size_t M = MQ;
  float* ws_base = ws;                   // lstm addresses gates relative to this
  ws += 1024;                            // 4 KB guard pad (bwd t=256 prefetch)
  float* gates   = ws; ws += M * 1024;   // [M][1024] fwd|bwd
  float* h_seq   = ws; ws += M * 256;
  float* proj1   = ws; ws += M * 64;
  float* s_src   = ws; ws += M * 8;
  float* s_trg   = ws; ws += M * 8;
  float* h1      = ws; ws += M * 64;
  float* m1      = ws; ws += 64;
  float* pooled  = ws; ws += 64 * 256;

  dim3 thr(256);

  // Stage A: fused embedding-gather + both input-gate GEMMs (K=300, N=1024)
  gemm_gates<<<dim3(MQ / GBM, 1024 / GBN), thr, 0, stream>>>(emb, ids, Wih_f, b_f, Wih_b, b_b, gates);

  // Stage B: BiLSTM recurrence (full-asm loop, U resident in v128-v255)
  lstm_kernel<<<128, 512, 0, stream>>>(ws_base, Whh_f, Whh_b, h_seq);

  // Stage C: GAT layer 1
  gemm_awt<<<dim3(MQ / BM, 1), thr, 0, stream>>>(h_seq, nullptr, g1_W, nullptr, proj1, MQ, 64, 256);
  srctrg_kernel<<<MQ / 256, thr, 0, stream>>>(proj1, g1_src, g1_trg, s_src, s_trg);
  gat1max_kernel<<<Bq, thr, 0, stream>>>(s_src, s_trg, m1);
  gat1_agg_kernel<<<Bq * 8, thr, 0, stream>>>(s_src, s_trg, proj1, m1, g1_b, h1);

  // Stage D: GAT layer 2 attention -> context attention -> softmax -> pooling
  gat2_att_pool_kernel<<<Bq, thr, 0, stream>>>(h1, g2_W, g2_src, g2_trg, ctx, h_seq, att_out, pooled);

  // Stage E: classifier head
  head_kernel<<<64, thr, 0, stream>>>(pooled, lin_W, lin_b, out_W, out_b, logits);
}

// Round 10
// 426.468 us; speedup vs baseline: 1.4620x; 1.2733x over previous
//
#include <hip/hip_runtime.h>
#include <math.h>
#include <stdint.h>

#define Bq 64
#define Lq 256
#define Eq 300
#define Hq 128
#define MQ (Bq*Lq)   // 16384

#define LRELU_S 0.2f

__device__ __forceinline__ float lrelu(float x) { return x > 0.f ? x : LRELU_S * x; }

// ---------------------------------------------------------------------------
// Generic tiled GEMM: C[m,n] = sum_k A[m,k]*W[n,k] (+ bias[n])
// ---------------------------------------------------------------------------
#define BM 64
#define BN 64
#define BK 16

__global__ __launch_bounds__(256) void gemm_awt(
    const float* __restrict__ Asrc, const int* __restrict__ ids,
    const float* __restrict__ W, const float* __restrict__ bias,
    float* __restrict__ C, int M, int N, int K)
{
  __shared__ float As[BK][BM + 4];
  __shared__ float Bs[BK][BN + 4];
  int tid = threadIdx.x;
  int tx = tid & 15, ty = tid >> 4;
  int row0 = blockIdx.x * BM, col0 = blockIdx.y * BN;

  int lrow = tid >> 2;          // 0..63
  int lk   = (tid & 3) << 2;    // 0,4,8,12

  const float* Arow;
  {
    int r = row0 + lrow;
    int id = ids ? ids[r] : r;
    Arow = Asrc + (size_t)id * K;
  }
  const float* Wrow = W + (size_t)(col0 + lrow) * K;

  float acc[4][4] = {};

  for (int k0 = 0; k0 < K; k0 += BK) {
    int kk = k0 + lk;
    float4 av, bv;
    if (kk + 3 < K) {
      av = *(const float4*)(Arow + kk);
      bv = *(const float4*)(Wrow + kk);
    } else {
      float a0 = (kk + 0 < K) ? Arow[kk + 0] : 0.f;
      float a1 = (kk + 1 < K) ? Arow[kk + 1] : 0.f;
      float a2 = (kk + 2 < K) ? Arow[kk + 2] : 0.f;
      float a3 = (kk + 3 < K) ? Arow[kk + 3] : 0.f;
      av = make_float4(a0, a1, a2, a3);
      float b0 = (kk + 0 < K) ? Wrow[kk + 0] : 0.f;
      float b1 = (kk + 1 < K) ? Wrow[kk + 1] : 0.f;
      float b2 = (kk + 2 < K) ? Wrow[kk + 2] : 0.f;
      float b3 = (kk + 3 < K) ? Wrow[kk + 3] : 0.f;
      bv = make_float4(b0, b1, b2, b3);
    }
    As[lk + 0][lrow] = av.x; As[lk + 1][lrow] = av.y;
    As[lk + 2][lrow] = av.z; As[lk + 3][lrow] = av.w;
    Bs[lk + 0][lrow] = bv.x; Bs[lk + 1][lrow] = bv.y;
    Bs[lk + 2][lrow] = bv.z; Bs[lk + 3][lrow] = bv.w;
    __syncthreads();

    #pragma unroll
    for (int k = 0; k < BK; ++k) {
      float4 a4 = *(const float4*)&As[k][ty * 4];
      float4 b4 = *(const float4*)&Bs[k][tx * 4];
      float a[4] = {a4.x, a4.y, a4.z, a4.w};
      float bb[4] = {b4.x, b4.y, b4.z, b4.w};
      #pragma unroll
      for (int i = 0; i < 4; ++i)
        #pragma unroll
        for (int j = 0; j < 4; ++j)
          acc[i][j] += a[i] * bb[j];
    }
    __syncthreads();
  }

  #pragma unroll
  for (int i = 0; i < 4; ++i) {
    int r = row0 + ty * 4 + i;
    #pragma unroll
    for (int j = 0; j < 4; ++j) {
      int cidx = col0 + tx * 4 + j;
      float v = acc[i][j] + (bias ? bias[cidx] : 0.f);
      C[(size_t)r * N + cidx] = v;
    }
  }
}

// ---------------------------------------------------------------------------
// Fused gates GEMM, 128x128 tile: C[m, 0:512] = emb[ids[m]] @ Wih_f^T + b_f
//                                 C[m, 512:1024] = emb[ids[m]] @ Wih_b^T + b_b
// ---------------------------------------------------------------------------
#define GBM 128
#define GBN 128
#define GBK 16

__global__ __launch_bounds__(256) void gemm_gates(
    const float* __restrict__ emb, const int* __restrict__ ids,
    const float* __restrict__ Wf, const float* __restrict__ bf,
    const float* __restrict__ Wb, const float* __restrict__ bb_,
    float* __restrict__ C)
{
  const int K = Eq;  // 300
  __shared__ float As[GBK][GBM + 4];
  __shared__ float Bs[GBK][GBN + 4];
  int tid = threadIdx.x;
  int tx = tid & 15, ty = tid >> 4;
  int row0 = blockIdx.x * GBM;
  int col0 = blockIdx.y * GBN;
  const float* W    = (col0 < 512) ? Wf : Wb;
  const float* bias = (col0 < 512) ? bf : bb_;
  int wcol0 = col0 & 511;

  int lrow = tid >> 1;
  int lk8  = (tid & 1) << 3;

  const float* Arow = emb + (size_t)ids[row0 + lrow] * K;
  const float* Wrow = W + (size_t)(wcol0 + lrow) * K;

  float acc[2][2][4][4] = {};

  for (int k0 = 0; k0 < K; k0 += GBK) {
    #pragma unroll
    for (int half = 0; half < 2; ++half) {
      int kk = k0 + lk8 + half * 4;
      float4 av, bv;
      if (kk + 3 < K) {
        av = *(const float4*)(Arow + kk);
        bv = *(const float4*)(Wrow + kk);
      } else {
        float aa[4], bw[4];
        #pragma unroll
        for (int q = 0; q < 4; ++q) {
          aa[q] = (kk + q < K) ? Arow[kk + q] : 0.f;
          bw[q] = (kk + q < K) ? Wrow[kk + q] : 0.f;
        }
        av = make_float4(aa[0], aa[1], aa[2], aa[3]);
        bv = make_float4(bw[0], bw[1], bw[2], bw[3]);
      }
      int kb = lk8 + half * 4;
      As[kb + 0][lrow] = av.x; As[kb + 1][lrow] = av.y;
      As[kb + 2][lrow] = av.z; As[kb + 3][lrow] = av.w;
      Bs[kb + 0][lrow] = bv.x; Bs[kb + 1][lrow] = bv.y;
      Bs[kb + 2][lrow] = bv.z; Bs[kb + 3][lrow] = bv.w;
    }
    __syncthreads();

    #pragma unroll
    for (int k = 0; k < GBK; ++k) {
      float4 a0 = *(const float4*)&As[k][ty * 4];
      float4 a1 = *(const float4*)&As[k][64 + ty * 4];
      float4 b0 = *(const float4*)&Bs[k][tx * 4];
      float4 b1 = *(const float4*)&Bs[k][64 + tx * 4];
      float av_[2][4] = {{a0.x, a0.y, a0.z, a0.w}, {a1.x, a1.y, a1.z, a1.w}};
      float bv_[2][4] = {{b0.x, b0.y, b0.z, b0.w}, {b1.x, b1.y, b1.z, b1.w}};
      #pragma unroll
      for (int ra = 0; ra < 2; ++ra)
        #pragma unroll
        for (int rb = 0; rb < 2; ++rb)
          #pragma unroll
          for (int i = 0; i < 4; ++i)
            #pragma unroll
            for (int j = 0; j < 4; ++j)
              acc[ra][rb][i][j] += av_[ra][i] * bv_[rb][j];
    }
    __syncthreads();
  }

  #pragma unroll
  for (int ra = 0; ra < 2; ++ra)
    #pragma unroll
    for (int i = 0; i < 4; ++i) {
      int r = row0 + ra * 64 + ty * 4 + i;
      #pragma unroll
      for (int rb = 0; rb < 2; ++rb)
        #pragma unroll
        for (int j = 0; j < 4; ++j) {
          int cc = rb * 64 + tx * 4 + j;
          C[(size_t)r * 1024 + col0 + cc] = acc[ra][rb][i][j] + bias[wcol0 + cc];
        }
    }
}

// ---------------------------------------------------------------------------
// BiLSTM recurrence — full-asm loop, v2: uniform-LDS-broadcast matvec.
// r8 proved U residency (v128-v255) but stayed at ~2900 cyc/step: the 256
// v_readlane->SGPR->v_fmac pairs carry a VALU-writes-SGPR hazard (wait
// states per pair) and double the instruction count. v2 broadcasts h via
// ds_read_b128 with a UNIFORM address (same-address LDS reads broadcast,
// conflict-free) — no SGPR involved, 32 DS ops + 128 fmacs per step.
// Reads run 6 quads deep (consume-issue distance ~144 cyc > ~120 cyc LDS
// latency) with lgkmcnt(5) waits; 4 round-robin accumulators break the fmac
// dependence chain.
// Register map (hard): v80-v98 temps/addr, v100-v123 six read slots,
// v128-v255 U row. s90 loop counter. No readlanes -> no SGPR hazards.
// Gate exchange via 4 ds_bpermute as in r8 (proven). Gates buffer has a
// 1024-float front pad for the bwd t=256 prefetch.
// ---------------------------------------------------------------------------
#define MVB(s0,s1,s2,s3, u0,u1,u2,u3, off) \
  "s_waitcnt lgkmcnt(5)\n" \
  "v_fmac_f32 v88, v" #s0 ", v" #u0 "\n" \
  "v_fmac_f32 v89, v" #s1 ", v" #u1 "\n" \
  "v_fmac_f32 v90, v" #s2 ", v" #u2 "\n" \
  "v_fmac_f32 v91, v" #s3 ", v" #u3 "\n" \
  "ds_read_b128 v[" #s0 ":" #s3 "], v81 offset:" #off "\n"

#define MVT(n, s0,s1,s2,s3, u0,u1,u2,u3) \
  "s_waitcnt lgkmcnt(" #n ")\n" \
  "v_fmac_f32 v88, v" #s0 ", v" #u0 "\n" \
  "v_fmac_f32 v89, v" #s1 ", v" #u1 "\n" \
  "v_fmac_f32 v90, v" #s2 ", v" #u2 "\n" \
  "v_fmac_f32 v91, v" #s3 ", v" #u3 "\n"

#define ULD(lo,hi,off) \
  "global_load_dwordx4 v[" #lo ":" #hi "], v80, %[ub] offset:" #off "\n"

__global__ __launch_bounds__(512, 1) void lstm_kernel(
    const float* __restrict__ ws_base,   // d_ws base; gates start at +1024 floats
    const float* __restrict__ Uf, const float* __restrict__ Ub,
    float* __restrict__ h_seq)
{
  __shared__ __align__(1024) float h_sh[2][Hq];
  int blk = blockIdx.x;      // 0..127
  int b = blk & 63;
  int dir = blk >> 6;
  int j = threadIdx.x;       // 0..511
  int lane = j & 63;
  int w = j >> 6;
  int gate = (lane >> 4) & 3;          // 0:i 1:f 2:g 3:o
  int hidx = (w << 4) | (lane & 15);   // 0..127
  int row = (gate << 7) | hidx;        // 0..511

  const float* U = dir ? Ub : Uf;
  int tt0 = dir ? (Lq - 1) : 0;

  unsigned uo  = (unsigned)row * (Hq * 4u);                     // byte off into U
  unsigned go0 = (1024u + (unsigned)(b * Lq + tt0) * 1024u
                  + (unsigned)dir * 512u + (unsigned)row) * 4u; // byte off from ws
  unsigned ho0 = ((unsigned)(b * Lq + tt0) * 256u
                  + (unsigned)dir * (unsigned)Hq + (unsigned)hidx) * 4u;
  int gd = dir ? -4096 : 4096;   // bytes per step in gates
  int hd = dir ? -1024 : 1024;   // bytes per step in h_seq

  unsigned lds_base = (unsigned)(uintptr_t)&h_sh[0][0];
  unsigned ldsr0 = lds_base;                              // uniform h read base
  unsigned ldsw0 = lds_base + 512u + (unsigned)hidx * 4u; // write buf1

  bool isg = (gate == 2);
  float klog = isg ? -2.8853900817779268f : -1.4426950408889634f; // -k*log2(e)
  float mc = isg ? 2.f : 1.f;
  float ac = isg ? -1.f : 0.f;
  int base4 = (lane & 15) * 4;
  int bp0 = base4, bp1 = base4 + 64, bp2 = base4 + 128, bp3 = base4 + 192;

  if (j < Hq) h_sh[0][j] = 0.f;
  __syncthreads();

  asm volatile(
    // ---- prologue ----
    "v_mov_b32 v80, %[uo]\n"
    "v_mov_b32 v81, %[ldsr0]\n"
    "v_mov_b32 v82, %[ldsw0]\n"
    "v_mov_b32 v83, %[go0]\n"
    "v_mov_b32 v84, %[ho0]\n"
    "v_mov_b32 v87, 0\n"               // c = 0
    "s_mov_b32 s90, 0\n"               // t = 0
    ULD(128,131,0)   ULD(132,135,16)  ULD(136,139,32)  ULD(140,143,48)
    ULD(144,147,64)  ULD(148,151,80)  ULD(152,155,96)  ULD(156,159,112)
    ULD(160,163,128) ULD(164,167,144) ULD(168,171,160) ULD(172,175,176)
    ULD(176,179,192) ULD(180,183,208) ULD(184,187,224) ULD(188,191,240)
    ULD(192,195,256) ULD(196,199,272) ULD(200,203,288) ULD(204,207,304)
    ULD(208,211,320) ULD(212,215,336) ULD(216,219,352) ULD(220,223,368)
    ULD(224,227,384) ULD(228,231,400) ULD(232,235,416) ULD(236,239,432)
    ULD(240,243,448) ULD(244,247,464) ULD(248,251,480) ULD(252,255,496)
    "global_load_dword v85, v83, %[wsb]\n"   // gcur (t=0)
    "s_waitcnt vmcnt(0)\n"
    // ---- time loop ----
    "Ltop_%=:\n"
    "v_add_u32 v83, %[gd], v83\n"
    "global_load_dword v86, v83, %[wsb]\n"   // prefetch gate t+1
    // issue 6 uniform h quads (broadcast reads, pipeline prime)
    "ds_read_b128 v[100:103], v81\n"
    "ds_read_b128 v[104:107], v81 offset:16\n"
    "ds_read_b128 v[108:111], v81 offset:32\n"
    "ds_read_b128 v[112:115], v81 offset:48\n"
    "ds_read_b128 v[116:119], v81 offset:64\n"
    "ds_read_b128 v[120:123], v81 offset:80\n"
    "v_mov_b32 v88, v85\n"                   // acc0 = gate input
    "v_mov_b32 v89, 0\n"
    "v_mov_b32 v90, 0\n"
    "v_mov_b32 v91, 0\n"
    // 32 quads: consume slot (q%6), refill at offset (q+6)*16 while q<=25
    MVB(100,101,102,103, 128,129,130,131, 96)
    MVB(104,105,106,107, 132,133,134,135, 112)
    MVB(108,109,110,111, 136,137,138,139, 128)
    MVB(112,113,114,115, 140,141,142,143, 144)
    MVB(116,117,118,119, 144,145,146,147, 160)
    MVB(120,121,122,123, 148,149,150,151, 176)
    MVB(100,101,102,103, 152,153,154,155, 192)
    MVB(104,105,106,107, 156,157,158,159, 208)
    MVB(108,109,110,111, 160,161,162,163, 224)
    MVB(112,113,114,115, 164,165,166,167, 240)
    MVB(116,117,118,119, 168,169,170,171, 256)
    MVB(120,121,122,123, 172,173,174,175, 272)
    MVB(100,101,102,103, 176,177,178,179, 288)
    MVB(104,105,106,107, 180,181,182,183, 304)
    MVB(108,109,110,111, 184,185,186,187, 320)
    MVB(112,113,114,115, 188,189,190,191, 336)
    MVB(116,117,118,119, 192,193,194,195, 352)
    MVB(120,121,122,123, 196,197,198,199, 368)
    MVB(100,101,102,103, 200,201,202,203, 384)
    MVB(104,105,106,107, 204,205,206,207, 400)
    MVB(108,109,110,111, 208,209,210,211, 416)
    MVB(112,113,114,115, 212,213,214,215, 432)
    MVB(116,117,118,119, 216,217,218,219, 448)
    MVB(120,121,122,123, 220,221,222,223, 464)
    MVB(100,101,102,103, 224,225,226,227, 480)
    MVB(104,105,106,107, 228,229,230,231, 496)
    MVT(5, 108,109,110,111, 232,233,234,235)
    MVT(4, 112,113,114,115, 236,237,238,239)
    MVT(3, 116,117,118,119, 240,241,242,243)
    MVT(2, 120,121,122,123, 244,245,246,247)
    MVT(1, 100,101,102,103, 248,249,250,251)
    MVT(0, 104,105,106,107, 252,253,254,255)
    "v_add_f32 v88, v88, v90\n"
    "v_add_f32 v89, v89, v91\n"
    "v_add_f32 v88, v88, v89\n"              // g
    // nl = mc * sigmoid(k*g) + ac   (rcp + 1 NR step)
    "v_mul_f32 v92, %[klog], v88\n"
    "v_exp_f32 v93, v92\n"
    "s_nop 1\n"
    "v_add_f32 v94, 1.0, v93\n"
    "v_rcp_f32 v95, v94\n"
    "s_nop 1\n"
    "v_mul_f32 v96, v94, v95\n"
    "v_sub_f32 v96, 2.0, v96\n"
    "v_mul_f32 v95, v95, v96\n"
    "v_fma_f32 v97, v95, %[mc], %[ac]\n"     // nl
    // gate exchange: i,f,g,o of my hidx from lanes base,+16,+32,+48
    "ds_bpermute_b32 v92, %[bp0], v97\n"
    "ds_bpermute_b32 v93, %[bp1], v97\n"
    "ds_bpermute_b32 v94, %[bp2], v97\n"
    "ds_bpermute_b32 v98, %[bp3], v97\n"
    "s_waitcnt lgkmcnt(0)\n"
    "v_mul_f32 v95, v92, v94\n"              // si*tg
    "v_fma_f32 v87, v93, v87, v95\n"         // c = sf*c + si*tg
    // h = so * tanh(c);  tanh(c) = 2*sigmoid(2c)-1
    "v_mul_f32 v92, 0xc038aa3b, v87\n"       // -2*log2e * c
    "v_exp_f32 v93, v92\n"
    "s_nop 1\n"
    "v_add_f32 v94, 1.0, v93\n"
    "v_rcp_f32 v95, v94\n"
    "s_nop 1\n"
    "v_mul_f32 v96, v94, v95\n"
    "v_sub_f32 v96, 2.0, v96\n"
    "v_mul_f32 v95, v95, v96\n"
    "v_fma_f32 v96, v95, 2.0, -1.0\n"        // tanh(c)
    "v_mul_f32 v96, v98, v96\n"              // h = so * tanh(c)
    // roll prefetched gate (load issued ~200 instr ago)
    "s_waitcnt vmcnt(0)\n"
    "v_mov_b32 v85, v86\n"
    // store h (4 gate-group lanes store same value to same addr: benign)
    "ds_write_b32 v82, v96\n"
    "global_store_dword v84, v96, %[hsb]\n"
    "v_add_u32 v84, %[hd], v84\n"
    "v_xor_b32 v81, 0x200, v81\n"            // toggle LDS read buffer
    "v_xor_b32 v82, 0x200, v82\n"            // toggle LDS write buffer
    "s_waitcnt lgkmcnt(0)\n"
    "s_barrier\n"
    "s_add_u32 s90, s90, 1\n"
    "s_cmp_lt_u32 s90, 256\n"
    "s_cbranch_scc1 Ltop_%=\n"
    "s_waitcnt vmcnt(0) lgkmcnt(0)\n"
    :
    : [wsb]"s"(ws_base), [hsb]"s"(h_seq), [ub]"s"(U),
      [gd]"s"(gd), [hd]"s"(hd),
      [uo]"v"(uo), [go0]"v"(go0), [ho0]"v"(ho0),
      [ldsr0]"v"(ldsr0), [ldsw0]"v"(ldsw0),
      [klog]"v"(klog), [mc]"v"(mc), [ac]"v"(ac),
      [bp0]"v"(bp0), [bp1]"v"(bp1), [bp2]"v"(bp2), [bp3]"v"(bp3)
    : "memory", "scc", "s90",
      "v80","v81","v82","v83","v84","v85","v86","v87","v88","v89",
      "v90","v91","v92","v93","v94","v95","v96","v97","v98",
      "v100","v101","v102","v103","v104","v105","v106","v107",
      "v108","v109","v110","v111","v112","v113","v114","v115",
      "v116","v117","v118","v119","v120","v121","v122","v123",
      "v128","v129","v130","v131","v132","v133","v134","v135",
      "v136","v137","v138","v139","v140","v141","v142","v143",
      "v144","v145","v146","v147","v148","v149","v150","v151",
      "v152","v153","v154","v155","v156","v157","v158","v159",
      "v160","v161","v162","v163","v164","v165","v166","v167",
      "v168","v169","v170","v171","v172","v173","v174","v175",
      "v176","v177","v178","v179","v180","v181","v182","v183",
      "v184","v185","v186","v187","v188","v189","v190","v191",
      "v192","v193","v194","v195","v196","v197","v198","v199",
      "v200","v201","v202","v203","v204","v205","v206","v207",
      "v208","v209","v210","v211","v212","v213","v214","v215",
      "v216","v217","v218","v219","v220","v221","v222","v223",
      "v224","v225","v226","v227","v228","v229","v230","v231",
      "v232","v233","v234","v235","v236","v237","v238","v239",
      "v240","v241","v242","v243","v244","v245","v246","v247",
      "v248","v249","v250","v251","v252","v253","v254","v255");
}
#undef MVB
#undef MVT
#undef ULD

// ---------------------------------------------------------------------------
// GAT1 attention-score projections: s_src/s_trg[b,l,h] from proj1 [M,64]
// ---------------------------------------------------------------------------
__global__ void srctrg_kernel(const float* __restrict__ proj1,
                              const float* __restrict__ a_src,
                              const float* __restrict__ a_trg,
                              float* __restrict__ s_src, float* __restrict__ s_trg)
{
  int m = blockIdx.x * blockDim.x + threadIdx.x;
  if (m >= MQ) return;
  const float* p = proj1 + (size_t)m * 64;
  #pragma unroll
  for (int h = 0; h < 8; ++h) {
    float ss = 0.f, st = 0.f;
    #pragma unroll
    for (int f = 0; f < 8; ++f) {
      float v = p[h * 8 + f];
      ss += v * a_src[h * 8 + f];
      st += v * a_trg[h * 8 + f];
    }
    s_src[(size_t)m * 8 + h] = ss;
    s_trg[(size_t)m * 8 + h] = st;
  }
}

// ---------------------------------------------------------------------------
// GAT1 per-graph max: m1[b] = lrelu( max_h ( max_s src + max_t trg ) )
// ---------------------------------------------------------------------------
__global__ __launch_bounds__(256) void gat1max_kernel(
    const float* __restrict__ s_src, const float* __restrict__ s_trg,
    float* __restrict__ m1)
{
  int b = blockIdx.x;
  int tid = threadIdx.x;
  int h = tid >> 5, r = tid & 31;
  float ms = -3.4e38f, mt = -3.4e38f;
  for (int s = r; s < Lq; s += 32) {
    ms = fmaxf(ms, s_src[((size_t)b * Lq + s) * 8 + h]);
    mt = fmaxf(mt, s_trg[((size_t)b * Lq + s) * 8 + h]);
  }
  #pragma unroll
  for (int o = 16; o > 0; o >>= 1) {
    ms = fmaxf(ms, __shfl_xor(ms, o, 32));
    mt = fmaxf(mt, __shfl_xor(mt, o, 32));
  }
  __shared__ float hh[8];
  if (r == 0) hh[h] = ms + mt;
  __syncthreads();
  if (tid == 0) {
    float mm = -3.4e38f;
    #pragma unroll
    for (int k = 0; k < 8; ++k) mm = fmaxf(mm, hh[k]);
    m1[b] = lrelu(mm);
  }
}

// ---------------------------------------------------------------------------
// GAT1 aggregation: block per (b,h); thread per target t.
// ---------------------------------------------------------------------------
__global__ __launch_bounds__(256) void gat1_agg_kernel(
    const float* __restrict__ s_src, const float* __restrict__ s_trg,
    const float* __restrict__ proj1, const float* __restrict__ m1,
    const float* __restrict__ g1_b, float* __restrict__ h1)
{
  int b = blockIdx.x >> 3;
  int h = blockIdx.x & 7;
  int t = threadIdx.x;
  __shared__ float src_s[Lq], trg_s[Lq];
  __shared__ float proj_s[Lq * 8];

  size_t base = (size_t)b * Lq;
  src_s[t] = s_src[(base + t) * 8 + h];
  trg_s[t] = s_trg[(base + t) * 8 + h];
  {
    const float4* pr = (const float4*)(proj1 + (base + t) * 64 + h * 8);
    float4* psh = (float4*)(proj_s + t * 8);
    psh[0] = pr[0];
    psh[1] = pr[1];
  }
  __syncthreads();

  float m = m1[b];
  float mytrg = trg_s[t];
  float den = 1e-16f;
  float acc[8] = {};
  for (int s = 0; s < Lq; ++s) {
    float w = __expf(lrelu(src_s[s] + mytrg) - m);
    den += w;
    const float* ps = proj_s + s * 8;
    #pragma unroll
    for (int f = 0; f < 8; ++f) acc[f] += w * ps[f];
  }
  float inv = 1.f / den;
  float* out = h1 + (base + t) * 64 + h * 8;
  #pragma unroll
  for (int f = 0; f < 8; ++f) {
    float v = acc[f] * inv + g1_b[h * 8 + f];
    out[f] = v > 0.f ? v : expm1f(v);   // ELU
  }
}

// ---------------------------------------------------------------------------
// block reductions over 256 threads (4 waves of 64)
// ---------------------------------------------------------------------------
__device__ __forceinline__ float block_max_256(float v, volatile float* red) {
  #pragma unroll
  for (int o = 32; o > 0; o >>= 1) v = fmaxf(v, __shfl_xor(v, o, 64));
  int tid = threadIdx.x;
  if ((tid & 63) == 0) red[tid >> 6] = v;
  __syncthreads();
  float r = fmaxf(fmaxf(red[0], red[1]), fmaxf(red[2], red[3]));
  __syncthreads();
  return r;
}
__device__ __forceinline__ float block_sum_256(float v, volatile float* red) {
  #pragma unroll
  for (int o = 32; o > 0; o >>= 1) v += __shfl_xor(v, o, 64);
  int tid = threadIdx.x;
  if ((tid & 63) == 0) red[tid >> 6] = v;
  __syncthreads();
  float r = red[0] + red[1] + red[2] + red[3];
  __syncthreads();
  return r;
}

// ---------------------------------------------------------------------------
// GAT2 (1 head, 1 feat) -> att weights -> softmax -> weighted-max pooling.
// ---------------------------------------------------------------------------
__global__ __launch_bounds__(256) void gat2_att_pool_kernel(
    const float* __restrict__ h1, const float* __restrict__ g2_W,
    const float* __restrict__ g2_src, const float* __restrict__ g2_trg,
    const float* __restrict__ ctx, const float* __restrict__ h_seq,
    float* __restrict__ att_out, float* __restrict__ pooled)
{
  int b = blockIdx.x;
  int tid = threadIdx.x;
  __shared__ float w2[64];
  __shared__ float src2[Lq], trg2[Lq], dq[Lq], att_sh[Lq];
  __shared__ float red[4];

  if (tid < 64) w2[tid] = g2_W[tid];
  __syncthreads();

  const float* hr = h1 + ((size_t)b * Lq + tid) * 64;
  float p = 0.f;
  #pragma unroll
  for (int k = 0; k < 64; ++k) p += hr[k] * w2[k];
  float a_s = g2_src[0], a_t = g2_trg[0];
  src2[tid] = p * a_s;
  trg2[tid] = p * a_t;
  __syncthreads();

  float ms = block_max_256(src2[tid], red);
  float mt = block_max_256(trg2[tid], red);
  float m2 = lrelu(ms + mt);

  float mytrg = trg2[tid];
  float den = 1e-16f;
  for (int s = 0; s < Lq; ++s)
    den += __expf(lrelu(src2[s] + mytrg) - m2);
  dq[tid] = ctx[tid] / den;
  __syncthreads();

  float mysrc = src2[tid];
  float raw = 0.f;
  for (int t = 0; t < Lq; ++t)
    raw += dq[t] * __expf(lrelu(mysrc + trg2[t]) - m2);

  float mr = block_max_256(raw, red);
  float e = __expf(raw - mr);
  float ssum = block_sum_256(e, red);
  float att = e / ssum;
  att_out[(size_t)b * Lq + tid] = att;
  att_sh[tid] = att;
  __syncthreads();

  float pm = -3.4e38f;
  for (int l = 0; l < Lq; ++l)
    pm = fmaxf(pm, h_seq[((size_t)b * Lq + l) * 256 + tid] * att_sh[l]);
  pooled[(size_t)b * 256 + tid] = pm;
}

// ---------------------------------------------------------------------------
// Head: grid(64) — one block per sample.
// ---------------------------------------------------------------------------
__global__ __launch_bounds__(256) void head_kernel(
    const float* __restrict__ pooled, const float* __restrict__ lin_W,
    const float* __restrict__ lin_b, const float* __restrict__ out_W,
    const float* __restrict__ out_b, float* __restrict__ logits)
{
  int i = blockIdx.x;
  int tid = threadIdx.x;
  int j = tid & 63, kq = tid >> 6;
  __shared__ float part[4][64];
  __shared__ float hcl[64];
  const float* pr = pooled + i * 256 + kq * 64;
  const float* wr = lin_W + j * 256 + kq * 64;
  float d = 0.f;
  #pragma unroll
  for (int k = 0; k < 64; ++k) d += pr[k] * wr[k];
  part[kq][j] = d;
  __syncthreads();
  if (tid < 64) {
    float v = part[0][j] + part[1][j] + part[2][j] + part[3][j] + lin_b[j];
    hcl[j] = fmaxf(v, 0.f);
  }
  __syncthreads();
  if (tid < 128) {
    int cc = tid >> 6, jj = tid & 63;
    float p = hcl[jj] * out_W[cc * 64 + jj];
    #pragma unroll
    for (int o = 32; o > 0; o >>= 1) p += __shfl_xor(p, o, 64);
    if (jj == 0) logits[i * 2 + cc] = p + out_b[cc];
  }
}

// ---------------------------------------------------------------------------
extern "C" void kernel_launch(void* const* d_in, const int* in_sizes, int n_in,
                              void* d_out, int out_size, void* d_ws, size_t ws_size,
                              hipStream_t stream)
{
  const int*   ids    = (const int*)  d_in[0];
  // d_in[1] = attention_mask (all ones by construction; unused)
  const float* emb    = (const float*)d_in[2];
  const float* Wih_f  = (const float*)d_in[3];
  const float* Whh_f  = (const float*)d_in[4];
  const float* b_f    = (const float*)d_in[5];
  const float* Wih_b  = (const float*)d_in[6];
  const float* Whh_b  = (const float*)d_in[7];
  const float* b_b    = (const float*)d_in[8];
  const float* g1_W   = (const float*)d_in[9];
  const float* g1_src = (const float*)d_in[10];
  const float* g1_trg = (const float*)d_in[11];
  const float* g1_b   = (const float*)d_in[12];
  const float* g2_W   = (const float*)d_in[13];
  const float* g2_src = (const float*)d_in[14];
  const float* g2_trg = (const float*)d_in[15];
  // d_in[16] = g2_b (unused)
  const float* ctx    = (const float*)d_in[17];
  const float* lin_W  = (const float*)d_in[18];
  const float* lin_b  = (const float*)d_in[19];
  const float* out_W  = (const float*)d_in[20];
  const float* out_b  = (const float*)d_in[21];

  float* out_f   = (float*)d_out;
  float* logits  = out_f;          // [64,2]
  float* att_out = out_f + 128;    // [64,256]

  float* ws = (float*)d_ws;
  const size_t M = MQ;
  float* ws_base = ws;                   // lstm addresses gates relative to this
  ws += 1024;                            // 4 KB guard pad (bwd t=256 prefetch)
  float* gates   = ws; ws += M * 1024;   // [M][1024] fwd|bwd
  float* h_seq   = ws; ws += M * 256;
  float* proj1   = ws; ws += M * 64;
  float* s_src   = ws; ws += M * 8;
  float* s_trg   = ws; ws += M * 8;
  float* h1      = ws; ws += M * 64;
  float* m1      = ws; ws += 64;
  float* pooled  = ws; ws += 64 * 256;

  dim3 thr(256);

  // Stage A: fused embedding-gather + both input-gate GEMMs (K=300, N=1024)
  gemm_gates<<<dim3(MQ / GBM, 1024 / GBN), thr, 0, stream>>>(emb, ids, Wih_f, b_f, Wih_b, b_b, gates);

  // Stage B: BiLSTM recurrence (full-asm, uniform-LDS-broadcast matvec)
  lstm_kernel<<<128, 512, 0, stream>>>(ws_base, Whh_f, Whh_b, h_seq);

  // Stage C: GAT layer 1
  gemm_awt<<<dim3(MQ / BM, 1), thr, 0, stream>>>(h_seq, nullptr, g1_W, nullptr, proj1, MQ, 64, 256);
  srctrg_kernel<<<MQ / 256, thr, 0, stream>>>(proj1, g1_src, g1_trg, s_src, s_trg);
  gat1max_kernel<<<Bq, thr, 0, stream>>>(s_src, s_trg, m1);
  gat1_agg_kernel<<<Bq * 8, thr, 0, stream>>>(s_src, s_trg, proj1, m1, g1_b, h1);

  // Stage D: GAT layer 2 attention -> context attention -> softmax -> pooling
  gat2_att_pool_kernel<<<Bq, thr, 0, stream>>>(h1, g2_W, g2_src, g2_trg, ctx, h_seq, att_out, pooled);

  // Stage E: classifier head
  head_kernel<<<64, thr, 0, stream>>>(pooled, lin_W, lin_b, out_W, out_b, logits);
}

// Round 11
// 363.403 us; speedup vs baseline: 1.7157x; 1.1735x over previous
//
#include <hip/hip_runtime.h>
#include <math.h>
#include <stdint.h>

#define Bq 64
#define Lq 256
#define Eq 300
#define Hq 128
#define MQ (Bq*Lq)   // 16384

#define LRELU_S 0.2f

__device__ __forceinline__ float lrelu(float x) { return x > 0.f ? x : LRELU_S * x; }

typedef short short8 __attribute__((ext_vector_type(8)));
typedef float f32x4v __attribute__((ext_vector_type(4)));

// fp32 -> bf16 round-to-nearest-even (values finite; no NaN handling needed)
__device__ __forceinline__ unsigned short f2bf(float x) {
  unsigned u = __float_as_uint(x);
  u += 0x7FFFu + ((u >> 16) & 1u);
  return (unsigned short)(u >> 16);
}
__device__ __forceinline__ float bf2f(unsigned short h) {
  return __uint_as_float(((unsigned)h) << 16);
}

// ---------------------------------------------------------------------------
// Generic tiled GEMM (fp32): C[m,n] = sum_k A[m,k]*W[n,k] (+ bias[n])
// (kept for the small GAT1 projection)
// ---------------------------------------------------------------------------
#define BM 64
#define BN 64
#define BK 16

__global__ __launch_bounds__(256) void gemm_awt(
    const float* __restrict__ Asrc, const int* __restrict__ ids,
    const float* __restrict__ W, const float* __restrict__ bias,
    float* __restrict__ C, int M, int N, int K)
{
  __shared__ float As[BK][BM + 4];
  __shared__ float Bs[BK][BN + 4];
  int tid = threadIdx.x;
  int tx = tid & 15, ty = tid >> 4;
  int row0 = blockIdx.x * BM, col0 = blockIdx.y * BN;

  int lrow = tid >> 2;          // 0..63
  int lk   = (tid & 3) << 2;    // 0,4,8,12

  const float* Arow;
  {
    int r = row0 + lrow;
    int id = ids ? ids[r] : r;
    Arow = Asrc + (size_t)id * K;
  }
  const float* Wrow = W + (size_t)(col0 + lrow) * K;

  float acc[4][4] = {};

  for (int k0 = 0; k0 < K; k0 += BK) {
    int kk = k0 + lk;
    float4 av, bv;
    if (kk + 3 < K) {
      av = *(const float4*)(Arow + kk);
      bv = *(const float4*)(Wrow + kk);
    } else {
      float a0 = (kk + 0 < K) ? Arow[kk + 0] : 0.f;
      float a1 = (kk + 1 < K) ? Arow[kk + 1] : 0.f;
      float a2 = (kk + 2 < K) ? Arow[kk + 2] : 0.f;
      float a3 = (kk + 3 < K) ? Arow[kk + 3] : 0.f;
      av = make_float4(a0, a1, a2, a3);
      float b0 = (kk + 0 < K) ? Wrow[kk + 0] : 0.f;
      float b1 = (kk + 1 < K) ? Wrow[kk + 1] : 0.f;
      float b2 = (kk + 2 < K) ? Wrow[kk + 2] : 0.f;
      float b3 = (kk + 3 < K) ? Wrow[kk + 3] : 0.f;
      bv = make_float4(b0, b1, b2, b3);
    }
    As[lk + 0][lrow] = av.x; As[lk + 1][lrow] = av.y;
    As[lk + 2][lrow] = av.z; As[lk + 3][lrow] = av.w;
    Bs[lk + 0][lrow] = bv.x; Bs[lk + 1][lrow] = bv.y;
    Bs[lk + 2][lrow] = bv.z; Bs[lk + 3][lrow] = bv.w;
    __syncthreads();

    #pragma unroll
    for (int k = 0; k < BK; ++k) {
      float4 a4 = *(const float4*)&As[k][ty * 4];
      float4 b4 = *(const float4*)&Bs[k][tx * 4];
      float a[4] = {a4.x, a4.y, a4.z, a4.w};
      float bb[4] = {b4.x, b4.y, b4.z, b4.w};
      #pragma unroll
      for (int i = 0; i < 4; ++i)
        #pragma unroll
        for (int j = 0; j < 4; ++j)
          acc[i][j] += a[i] * bb[j];
    }
    __syncthreads();
  }

  #pragma unroll
  for (int i = 0; i < 4; ++i) {
    int r = row0 + ty * 4 + i;
    #pragma unroll
    for (int j = 0; j < 4; ++j) {
      int cidx = col0 + tx * 4 + j;
      float v = acc[i][j] + (bias ? bias[cidx] : 0.f);
      C[(size_t)r * N + cidx] = v;
    }
  }
}

// ---------------------------------------------------------------------------
// Gates GEMM via bf16x2-split MFMA.
// C[m, 0:512] = emb[ids[m]] @ Wih_f^T + b_f ; C[m,512:1024] = ... Wih_b^T + b_b
// fp32 = hi(bf16) + lo(bf16); A.B = Ah.Bh + Ah.Bl + Al.Bh (drop 2^-18 term).
// 128x128 tile, 4 waves (2x2), K-step 32, v_mfma_f32_16x16x32_bf16.
// LDS tiles [128 rows][32 k] bf16, 16B chunks XOR-swizzled by (row>>2)&3
// -> fragment ds_read_b128 is 2-way-max bank aliased (free, G4/m136).
// Fragment layouts: A/B lane l: row/col = l&15, k = 8*(l>>4)+j;
// D (m89-verified): col = l&15, row = (l>>4)*4 + reg.
// ---------------------------------------------------------------------------
__global__ __launch_bounds__(256) void gemm_gates_mfma(
    const float* __restrict__ emb, const int* __restrict__ ids,
    const float* __restrict__ Wf, const float* __restrict__ bf,
    const float* __restrict__ Wb, const float* __restrict__ bb_,
    float* __restrict__ C)
{
  __shared__ __align__(16) short Ah[128 * 32];
  __shared__ __align__(16) short Al[128 * 32];
  __shared__ __align__(16) short Bh[128 * 32];
  __shared__ __align__(16) short Bl[128 * 32];
  __shared__ int ids_s[128];

  int tid = threadIdx.x;
  int row0 = blockIdx.x * 128;
  int col0 = blockIdx.y * 128;             // 0..896; each block in one half
  const float* W    = (col0 < 512) ? Wf : Wb;
  const float* bias = (col0 < 512) ? bf : bb_;
  int wcol0 = col0 & 511;

  if (tid < 128) ids_s[tid] = ids[row0 + tid];
  __syncthreads();

  int l  = tid & 63, wv = tid >> 6;
  int wm = wv >> 1,  wn = wv & 1;          // 2x2 waves, each 64x64
  int kq = l >> 4,   rl = l & 15;

  f32x4v acc[4][4] = {};

  for (int k0 = 0; k0 < 300; k0 += 32) {
    // ---- stage: fp32 -> (hi,lo) bf16 into swizzled LDS ----
    #pragma unroll
    for (int p = 0; p < 4; ++p) {
      int idx = p * 256 + tid;             // 1024 float4 slots per matrix
      int row = idx >> 3, c4 = idx & 7;    // c4: which float4 of the 32-k row
      int gk = k0 + c4 * 4;
      float4 av = make_float4(0.f, 0.f, 0.f, 0.f);
      float4 bv = make_float4(0.f, 0.f, 0.f, 0.f);
      if (gk < 300) {                      // 300%4==0: chunk fully valid or not
        av = *(const float4*)(emb + (size_t)ids_s[row] * 300 + gk);
        bv = *(const float4*)(W + (size_t)(wcol0 + row) * 300 + gk);
      }
      int chunk = (c4 >> 1) ^ ((row >> 2) & 3);
      int off = row * 32 + chunk * 8 + (c4 & 1) * 4;   // short index, 8B gran
      {
        unsigned short h0 = f2bf(av.x), h1 = f2bf(av.y), h2 = f2bf(av.z), h3 = f2bf(av.w);
        unsigned short l0 = f2bf(av.x - bf2f(h0)), l1 = f2bf(av.y - bf2f(h1));
        unsigned short l2 = f2bf(av.z - bf2f(h2)), l3 = f2bf(av.w - bf2f(h3));
        uint2 ph; ph.x = (unsigned)h0 | ((unsigned)h1 << 16); ph.y = (unsigned)h2 | ((unsigned)h3 << 16);
        uint2 pl; pl.x = (unsigned)l0 | ((unsigned)l1 << 16); pl.y = (unsigned)l2 | ((unsigned)l3 << 16);
        *(uint2*)&Ah[off] = ph;
        *(uint2*)&Al[off] = pl;
      }
      {
        unsigned short h0 = f2bf(bv.x), h1 = f2bf(bv.y), h2 = f2bf(bv.z), h3 = f2bf(bv.w);
        unsigned short l0 = f2bf(bv.x - bf2f(h0)), l1 = f2bf(bv.y - bf2f(h1));
        unsigned short l2 = f2bf(bv.z - bf2f(h2)), l3 = f2bf(bv.w - bf2f(h3));
        uint2 ph; ph.x = (unsigned)h0 | ((unsigned)h1 << 16); ph.y = (unsigned)h2 | ((unsigned)h3 << 16);
        uint2 pl; pl.x = (unsigned)l0 | ((unsigned)l1 << 16); pl.y = (unsigned)l2 | ((unsigned)l3 << 16);
        *(uint2*)&Bh[off] = ph;
        *(uint2*)&Bl[off] = pl;
      }
    }
    __syncthreads();

    // ---- fragments + MFMA ----
    short8 ah[4], al_[4], bh[4], bl[4];
    #pragma unroll
    for (int f = 0; f < 4; ++f) {
      int ar = wm * 64 + f * 16 + rl;
      int ac = kq ^ ((ar >> 2) & 3);
      ah[f]  = *(const short8*)&Ah[ar * 32 + ac * 8];
      al_[f] = *(const short8*)&Al[ar * 32 + ac * 8];
      int br = wn * 64 + f * 16 + rl;
      int bc = kq ^ ((br >> 2) & 3);
      bh[f]  = *(const short8*)&Bh[br * 32 + bc * 8];
      bl[f]  = *(const short8*)&Bl[br * 32 + bc * 8];
    }
    #pragma unroll
    for (int fm = 0; fm < 4; ++fm)
      #pragma unroll
      for (int fn = 0; fn < 4; ++fn) {
        acc[fm][fn] = __builtin_amdgcn_mfma_f32_16x16x32_bf16(ah[fm],  bh[fn], acc[fm][fn], 0, 0, 0);
        acc[fm][fn] = __builtin_amdgcn_mfma_f32_16x16x32_bf16(ah[fm],  bl[fn], acc[fm][fn], 0, 0, 0);
        acc[fm][fn] = __builtin_amdgcn_mfma_f32_16x16x32_bf16(al_[fm], bh[fn], acc[fm][fn], 0, 0, 0);
      }
    __syncthreads();
  }

  // ---- epilogue: D layout col=l&15, row=(l>>4)*4+reg (m89-verified) ----
  int fq = l >> 4;
  #pragma unroll
  for (int fm = 0; fm < 4; ++fm) {
    #pragma unroll
    for (int fn = 0; fn < 4; ++fn) {
      int gr = row0 + wm * 64 + fm * 16 + fq * 4;
      int lc = wn * 64 + fn * 16 + rl;
      float bsv = bias[wcol0 + lc];
      #pragma unroll
      for (int i = 0; i < 4; ++i)
        C[(size_t)(gr + i) * 1024 + col0 + lc] = acc[fm][fn][i] + bsv;
    }
  }
}

// ---------------------------------------------------------------------------
// BiLSTM recurrence — full-asm loop, uniform-LDS-broadcast matvec (r9: 198us).
// ---------------------------------------------------------------------------
#define MVB(s0,s1,s2,s3, u0,u1,u2,u3, off) \
  "s_waitcnt lgkmcnt(5)\n" \
  "v_fmac_f32 v88, v" #s0 ", v" #u0 "\n" \
  "v_fmac_f32 v89, v" #s1 ", v" #u1 "\n" \
  "v_fmac_f32 v90, v" #s2 ", v" #u2 "\n" \
  "v_fmac_f32 v91, v" #s3 ", v" #u3 "\n" \
  "ds_read_b128 v[" #s0 ":" #s3 "], v81 offset:" #off "\n"

#define MVT(n, s0,s1,s2,s3, u0,u1,u2,u3) \
  "s_waitcnt lgkmcnt(" #n ")\n" \
  "v_fmac_f32 v88, v" #s0 ", v" #u0 "\n" \
  "v_fmac_f32 v89, v" #s1 ", v" #u1 "\n" \
  "v_fmac_f32 v90, v" #s2 ", v" #u2 "\n" \
  "v_fmac_f32 v91, v" #s3 ", v" #u3 "\n"

#define ULD(lo,hi,off) \
  "global_load_dwordx4 v[" #lo ":" #hi "], v80, %[ub] offset:" #off "\n"

__global__ __launch_bounds__(512, 1) void lstm_kernel(
    const float* __restrict__ ws_base,   // d_ws base; gates start at +1024 floats
    const float* __restrict__ Uf, const float* __restrict__ Ub,
    float* __restrict__ h_seq)
{
  __shared__ __align__(1024) float h_sh[2][Hq];
  int blk = blockIdx.x;      // 0..127
  int b = blk & 63;
  int dir = blk >> 6;
  int j = threadIdx.x;       // 0..511
  int lane = j & 63;
  int w = j >> 6;
  int gate = (lane >> 4) & 3;          // 0:i 1:f 2:g 3:o
  int hidx = (w << 4) | (lane & 15);   // 0..127
  int row = (gate << 7) | hidx;        // 0..511

  const float* U = dir ? Ub : Uf;
  int tt0 = dir ? (Lq - 1) : 0;

  unsigned uo  = (unsigned)row * (Hq * 4u);
  unsigned go0 = (1024u + (unsigned)(b * Lq + tt0) * 1024u
                  + (unsigned)dir * 512u + (unsigned)row) * 4u;
  unsigned ho0 = ((unsigned)(b * Lq + tt0) * 256u
                  + (unsigned)dir * (unsigned)Hq + (unsigned)hidx) * 4u;
  int gd = dir ? -4096 : 4096;
  int hd = dir ? -1024 : 1024;

  unsigned lds_base = (unsigned)(uintptr_t)&h_sh[0][0];
  unsigned ldsr0 = lds_base;
  unsigned ldsw0 = lds_base + 512u + (unsigned)hidx * 4u;

  bool isg = (gate == 2);
  float klog = isg ? -2.8853900817779268f : -1.4426950408889634f;
  float mc = isg ? 2.f : 1.f;
  float ac = isg ? -1.f : 0.f;
  int base4 = (lane & 15) * 4;
  int bp0 = base4, bp1 = base4 + 64, bp2 = base4 + 128, bp3 = base4 + 192;

  if (j < Hq) h_sh[0][j] = 0.f;
  __syncthreads();

  asm volatile(
    "v_mov_b32 v80, %[uo]\n"
    "v_mov_b32 v81, %[ldsr0]\n"
    "v_mov_b32 v82, %[ldsw0]\n"
    "v_mov_b32 v83, %[go0]\n"
    "v_mov_b32 v84, %[ho0]\n"
    "v_mov_b32 v87, 0\n"
    "s_mov_b32 s90, 0\n"
    ULD(128,131,0)   ULD(132,135,16)  ULD(136,139,32)  ULD(140,143,48)
    ULD(144,147,64)  ULD(148,151,80)  ULD(152,155,96)  ULD(156,159,112)
    ULD(160,163,128) ULD(164,167,144) ULD(168,171,160) ULD(172,175,176)
    ULD(176,179,192) ULD(180,183,208) ULD(184,187,224) ULD(188,191,240)
    ULD(192,195,256) ULD(196,199,272) ULD(200,203,288) ULD(204,207,304)
    ULD(208,211,320) ULD(212,215,336) ULD(216,219,352) ULD(220,223,368)
    ULD(224,227,384) ULD(228,231,400) ULD(232,235,416) ULD(236,239,432)
    ULD(240,243,448) ULD(244,247,464) ULD(248,251,480) ULD(252,255,496)
    "global_load_dword v85, v83, %[wsb]\n"
    "s_waitcnt vmcnt(0)\n"
    "Ltop_%=:\n"
    "v_add_u32 v83, %[gd], v83\n"
    "global_load_dword v86, v83, %[wsb]\n"
    "ds_read_b128 v[100:103], v81\n"
    "ds_read_b128 v[104:107], v81 offset:16\n"
    "ds_read_b128 v[108:111], v81 offset:32\n"
    "ds_read_b128 v[112:115], v81 offset:48\n"
    "ds_read_b128 v[116:119], v81 offset:64\n"
    "ds_read_b128 v[120:123], v81 offset:80\n"
    "v_mov_b32 v88, v85\n"
    "v_mov_b32 v89, 0\n"
    "v_mov_b32 v90, 0\n"
    "v_mov_b32 v91, 0\n"
    MVB(100,101,102,103, 128,129,130,131, 96)
    MVB(104,105,106,107, 132,133,134,135, 112)
    MVB(108,109,110,111, 136,137,138,139, 128)
    MVB(112,113,114,115, 140,141,142,143, 144)
    MVB(116,117,118,119, 144,145,146,147, 160)
    MVB(120,121,122,123, 148,149,150,151, 176)
    MVB(100,101,102,103, 152,153,154,155, 192)
    MVB(104,105,106,107, 156,157,158,159, 208)
    MVB(108,109,110,111, 160,161,162,163, 224)
    MVB(112,113,114,115, 164,165,166,167, 240)
    MVB(116,117,118,119, 168,169,170,171, 256)
    MVB(120,121,122,123, 172,173,174,175, 272)
    MVB(100,101,102,103, 176,177,178,179, 288)
    MVB(104,105,106,107, 180,181,182,183, 304)
    MVB(108,109,110,111, 184,185,186,187, 320)
    MVB(112,113,114,115, 188,189,190,191, 336)
    MVB(116,117,118,119, 192,193,194,195, 352)
    MVB(120,121,122,123, 196,197,198,199, 368)
    MVB(100,101,102,103, 200,201,202,203, 384)
    MVB(104,105,106,107, 204,205,206,207, 400)
    MVB(108,109,110,111, 208,209,210,211, 416)
    MVB(112,113,114,115, 212,213,214,215, 432)
    MVB(116,117,118,119, 216,217,218,219, 448)
    MVB(120,121,122,123, 220,221,222,223, 464)
    MVB(100,101,102,103, 224,225,226,227, 480)
    MVB(104,105,106,107, 228,229,230,231, 496)
    MVT(5, 108,109,110,111, 232,233,234,235)
    MVT(4, 112,113,114,115, 236,237,238,239)
    MVT(3, 116,117,118,119, 240,241,242,243)
    MVT(2, 120,121,122,123, 244,245,246,247)
    MVT(1, 100,101,102,103, 248,249,250,251)
    MVT(0, 104,105,106,107, 252,253,254,255)
    "v_add_f32 v88, v88, v90\n"
    "v_add_f32 v89, v89, v91\n"
    "v_add_f32 v88, v88, v89\n"
    "v_mul_f32 v92, %[klog], v88\n"
    "v_exp_f32 v93, v92\n"
    "s_nop 1\n"
    "v_add_f32 v94, 1.0, v93\n"
    "v_rcp_f32 v95, v94\n"
    "s_nop 1\n"
    "v_mul_f32 v96, v94, v95\n"
    "v_sub_f32 v96, 2.0, v96\n"
    "v_mul_f32 v95, v95, v96\n"
    "v_fma_f32 v97, v95, %[mc], %[ac]\n"
    "ds_bpermute_b32 v92, %[bp0], v97\n"
    "ds_bpermute_b32 v93, %[bp1], v97\n"
    "ds_bpermute_b32 v94, %[bp2], v97\n"
    "ds_bpermute_b32 v98, %[bp3], v97\n"
    "s_waitcnt lgkmcnt(0)\n"
    "v_mul_f32 v95, v92, v94\n"
    "v_fma_f32 v87, v93, v87, v95\n"
    "v_mul_f32 v92, 0xc038aa3b, v87\n"
    "v_exp_f32 v93, v92\n"
    "s_nop 1\n"
    "v_add_f32 v94, 1.0, v93\n"
    "v_rcp_f32 v95, v94\n"
    "s_nop 1\n"
    "v_mul_f32 v96, v94, v95\n"
    "v_sub_f32 v96, 2.0, v96\n"
    "v_mul_f32 v95, v95, v96\n"
    "v_fma_f32 v96, v95, 2.0, -1.0\n"
    "v_mul_f32 v96, v98, v96\n"
    "s_waitcnt vmcnt(0)\n"
    "v_mov_b32 v85, v86\n"
    "ds_write_b32 v82, v96\n"
    "global_store_dword v84, v96, %[hsb]\n"
    "v_add_u32 v84, %[hd], v84\n"
    "v_xor_b32 v81, 0x200, v81\n"
    "v_xor_b32 v82, 0x200, v82\n"
    "s_waitcnt lgkmcnt(0)\n"
    "s_barrier\n"
    "s_add_u32 s90, s90, 1\n"
    "s_cmp_lt_u32 s90, 256\n"
    "s_cbranch_scc1 Ltop_%=\n"
    "s_waitcnt vmcnt(0) lgkmcnt(0)\n"
    :
    : [wsb]"s"(ws_base), [hsb]"s"(h_seq), [ub]"s"(U),
      [gd]"s"(gd), [hd]"s"(hd),
      [uo]"v"(uo), [go0]"v"(go0), [ho0]"v"(ho0),
      [ldsr0]"v"(ldsr0), [ldsw0]"v"(ldsw0),
      [klog]"v"(klog), [mc]"v"(mc), [ac]"v"(ac),
      [bp0]"v"(bp0), [bp1]"v"(bp1), [bp2]"v"(bp2), [bp3]"v"(bp3)
    : "memory", "scc", "s90",
      "v80","v81","v82","v83","v84","v85","v86","v87","v88","v89",
      "v90","v91","v92","v93","v94","v95","v96","v97","v98",
      "v100","v101","v102","v103","v104","v105","v106","v107",
      "v108","v109","v110","v111","v112","v113","v114","v115",
      "v116","v117","v118","v119","v120","v121","v122","v123",
      "v128","v129","v130","v131","v132","v133","v134","v135",
      "v136","v137","v138","v139","v140","v141","v142","v143",
      "v144","v145","v146","v147","v148","v149","v150","v151",
      "v152","v153","v154","v155","v156","v157","v158","v159",
      "v160","v161","v162","v163","v164","v165","v166","v167",
      "v168","v169","v170","v171","v172","v173","v174","v175",
      "v176","v177","v178","v179","v180","v181","v182","v183",
      "v184","v185","v186","v187","v188","v189","v190","v191",
      "v192","v193","v194","v195","v196","v197","v198","v199",
      "v200","v201","v202","v203","v204","v205","v206","v207",
      "v208","v209","v210","v211","v212","v213","v214","v215",
      "v216","v217","v218","v219","v220","v221","v222","v223",
      "v224","v225","v226","v227","v228","v229","v230","v231",
      "v232","v233","v234","v235","v236","v237","v238","v239",
      "v240","v241","v242","v243","v244","v245","v246","v247",
      "v248","v249","v250","v251","v252","v253","v254","v255");
}
#undef MVB
#undef MVT
#undef ULD

// ---------------------------------------------------------------------------
// GAT1 attention-score projections
// ---------------------------------------------------------------------------
__global__ void srctrg_kernel(const float* __restrict__ proj1,
                              const float* __restrict__ a_src,
                              const float* __restrict__ a_trg,
                              float* __restrict__ s_src, float* __restrict__ s_trg)
{
  int m = blockIdx.x * blockDim.x + threadIdx.x;
  if (m >= MQ) return;
  const float* p = proj1 + (size_t)m * 64;
  #pragma unroll
  for (int h = 0; h < 8; ++h) {
    float ss = 0.f, st = 0.f;
    #pragma unroll
    for (int f = 0; f < 8; ++f) {
      float v = p[h * 8 + f];
      ss += v * a_src[h * 8 + f];
      st += v * a_trg[h * 8 + f];
    }
    s_src[(size_t)m * 8 + h] = ss;
    s_trg[(size_t)m * 8 + h] = st;
  }
}

// ---------------------------------------------------------------------------
// GAT1 per-graph max
// ---------------------------------------------------------------------------
__global__ __launch_bounds__(256) void gat1max_kernel(
    const float* __restrict__ s_src, const float* __restrict__ s_trg,
    float* __restrict__ m1)
{
  int b = blockIdx.x;
  int tid = threadIdx.x;
  int h = tid >> 5, r = tid & 31;
  float ms = -3.4e38f, mt = -3.4e38f;
  for (int s = r; s < Lq; s += 32) {
    ms = fmaxf(ms, s_src[((size_t)b * Lq + s) * 8 + h]);
    mt = fmaxf(mt, s_trg[((size_t)b * Lq + s) * 8 + h]);
  }
  #pragma unroll
  for (int o = 16; o > 0; o >>= 1) {
    ms = fmaxf(ms, __shfl_xor(ms, o, 32));
    mt = fmaxf(mt, __shfl_xor(mt, o, 32));
  }
  __shared__ float hh[8];
  if (r == 0) hh[h] = ms + mt;
  __syncthreads();
  if (tid == 0) {
    float mm = -3.4e38f;
    #pragma unroll
    for (int k = 0; k < 8; ++k) mm = fmaxf(mm, hh[k]);
    m1[b] = lrelu(mm);
  }
}

// ---------------------------------------------------------------------------
// GAT1 aggregation
// ---------------------------------------------------------------------------
__global__ __launch_bounds__(256) void gat1_agg_kernel(
    const float* __restrict__ s_src, const float* __restrict__ s_trg,
    const float* __restrict__ proj1, const float* __restrict__ m1,
    const float* __restrict__ g1_b, float* __restrict__ h1)
{
  int b = blockIdx.x >> 3;
  int h = blockIdx.x & 7;
  int t = threadIdx.x;
  __shared__ float src_s[Lq], trg_s[Lq];
  __shared__ float proj_s[Lq * 8];

  size_t base = (size_t)b * Lq;
  src_s[t] = s_src[(base + t) * 8 + h];
  trg_s[t] = s_trg[(base + t) * 8 + h];
  {
    const float4* pr = (const float4*)(proj1 + (base + t) * 64 + h * 8);
    float4* psh = (float4*)(proj_s + t * 8);
    psh[0] = pr[0];
    psh[1] = pr[1];
  }
  __syncthreads();

  float m = m1[b];
  float mytrg = trg_s[t];
  float den = 1e-16f;
  float acc[8] = {};
  for (int s = 0; s < Lq; ++s) {
    float w = __expf(lrelu(src_s[s] + mytrg) - m);
    den += w;
    const float* ps = proj_s + s * 8;
    #pragma unroll
    for (int f = 0; f < 8; ++f) acc[f] += w * ps[f];
  }
  float inv = 1.f / den;
  float* out = h1 + (base + t) * 64 + h * 8;
  #pragma unroll
  for (int f = 0; f < 8; ++f) {
    float v = acc[f] * inv + g1_b[h * 8 + f];
    out[f] = v > 0.f ? v : expm1f(v);   // ELU
  }
}

// ---------------------------------------------------------------------------
// block reductions over 256 threads
// ---------------------------------------------------------------------------
__device__ __forceinline__ float block_max_256(float v, volatile float* red) {
  #pragma unroll
  for (int o = 32; o > 0; o >>= 1) v = fmaxf(v, __shfl_xor(v, o, 64));
  int tid = threadIdx.x;
  if ((tid & 63) == 0) red[tid >> 6] = v;
  __syncthreads();
  float r = fmaxf(fmaxf(red[0], red[1]), fmaxf(red[2], red[3]));
  __syncthreads();
  return r;
}
__device__ __forceinline__ float block_sum_256(float v, volatile float* red) {
  #pragma unroll
  for (int o = 32; o > 0; o >>= 1) v += __shfl_xor(v, o, 64);
  int tid = threadIdx.x;
  if ((tid & 63) == 0) red[tid >> 6] = v;
  __syncthreads();
  float r = red[0] + red[1] + red[2] + red[3];
  __syncthreads();
  return r;
}

// ---------------------------------------------------------------------------
// GAT2 -> att -> softmax -> weighted-max pooling
// ---------------------------------------------------------------------------
__global__ __launch_bounds__(256) void gat2_att_pool_kernel(
    const float* __restrict__ h1, const float* __restrict__ g2_W,
    const float* __restrict__ g2_src, const float* __restrict__ g2_trg,
    const float* __restrict__ ctx, const float* __restrict__ h_seq,
    float* __restrict__ att_out, float* __restrict__ pooled)
{
  int b = blockIdx.x;
  int tid = threadIdx.x;
  __shared__ float w2[64];
  __shared__ float src2[Lq], trg2[Lq], dq[Lq], att_sh[Lq];
  __shared__ float red[4];

  if (tid < 64) w2[tid] = g2_W[tid];
  __syncthreads();

  const float* hr = h1 + ((size_t)b * Lq + tid) * 64;
  float p = 0.f;
  #pragma unroll
  for (int k = 0; k < 64; ++k) p += hr[k] * w2[k];
  float a_s = g2_src[0], a_t = g2_trg[0];
  src2[tid] = p * a_s;
  trg2[tid] = p * a_t;
  __syncthreads();

  float ms = block_max_256(src2[tid], red);
  float mt = block_max_256(trg2[tid], red);
  float m2 = lrelu(ms + mt);

  float mytrg = trg2[tid];
  float den = 1e-16f;
  for (int s = 0; s < Lq; ++s)
    den += __expf(lrelu(src2[s] + mytrg) - m2);
  dq[tid] = ctx[tid] / den;
  __syncthreads();

  float mysrc = src2[tid];
  float raw = 0.f;
  for (int t = 0; t < Lq; ++t)
    raw += dq[t] * __expf(lrelu(mysrc + trg2[t]) - m2);

  float mr = block_max_256(raw, red);
  float e = __expf(raw - mr);
  float ssum = block_sum_256(e, red);
  float att = e / ssum;
  att_out[(size_t)b * Lq + tid] = att;
  att_sh[tid] = att;
  __syncthreads();

  float pm = -3.4e38f;
  for (int l = 0; l < Lq; ++l)
    pm = fmaxf(pm, h_seq[((size_t)b * Lq + l) * 256 + tid] * att_sh[l]);
  pooled[(size_t)b * 256 + tid] = pm;
}

// ---------------------------------------------------------------------------
// Head: grid(64)
// ---------------------------------------------------------------------------
__global__ __launch_bounds__(256) void head_kernel(
    const float* __restrict__ pooled, const float* __restrict__ lin_W,
    const float* __restrict__ lin_b, const float* __restrict__ out_W,
    const float* __restrict__ out_b, float* __restrict__ logits)
{
  int i = blockIdx.x;
  int tid = threadIdx.x;
  int j = tid & 63, kq = tid >> 6;
  __shared__ float part[4][64];
  __shared__ float hcl[64];
  const float* pr = pooled + i * 256 + kq * 64;
  const float* wr = lin_W + j * 256 + kq * 64;
  float d = 0.f;
  #pragma unroll
  for (int k = 0; k < 64; ++k) d += pr[k] * wr[k];
  part[kq][j] = d;
  __syncthreads();
  if (tid < 64) {
    float v = part[0][j] + part[1][j] + part[2][j] + part[3][j] + lin_b[j];
    hcl[j] = fmaxf(v, 0.f);
  }
  __syncthreads();
  if (tid < 128) {
    int cc = tid >> 6, jj = tid & 63;
    float p = hcl[jj] * out_W[cc * 64 + jj];
    #pragma unroll
    for (int o = 32; o > 0; o >>= 1) p += __shfl_xor(p, o, 64);
    if (jj == 0) logits[i * 2 + cc] = p + out_b[cc];
  }
}

// ---------------------------------------------------------------------------
extern "C" void kernel_launch(void* const* d_in, const int* in_sizes, int n_in,
                              void* d_out, int out_size, void* d_ws, size_t ws_size,
                              hipStream_t stream)
{
  const int*   ids    = (const int*)  d_in[0];
  // d_in[1] = attention_mask (all ones by construction; unused)
  const float* emb    = (const float*)d_in[2];
  const float* Wih_f  = (const float*)d_in[3];
  const float* Whh_f  = (const float*)d_in[4];
  const float* b_f    = (const float*)d_in[5];
  const float* Wih_b  = (const float*)d_in[6];
  const float* Whh_b  = (const float*)d_in[7];
  const float* b_b    = (const float*)d_in[8];
  const float* g1_W   = (const float*)d_in[9];
  const float* g1_src = (const float*)d_in[10];
  const float* g1_trg = (const float*)d_in[11];
  const float* g1_b   = (const float*)d_in[12];
  const float* g2_W   = (const float*)d_in[13];
  const float* g2_src = (const float*)d_in[14];
  const float* g2_trg = (const float*)d_in[15];
  // d_in[16] = g2_b (unused)
  const float* ctx    = (const float*)d_in[17];
  const float* lin_W  = (const float*)d_in[18];
  const float* lin_b  = (const float*)d_in[19];
  const float* out_W  = (const float*)d_in[20];
  const float* out_b  = (const float*)d_in[21];

  float* out_f   = (float*)d_out;
  float* logits  = out_f;          // [64,2]
  float* att_out = out_f + 128;    // [64,256]

  float* ws = (float*)d_ws;
  const size_t M = MQ;
  float* ws_base = ws;                   // lstm addresses gates relative to this
  ws += 1024;                            // 4 KB guard pad (bwd t=256 prefetch)
  float* gates   = ws; ws += M * 1024;   // [M][1024] fwd|bwd
  float* h_seq   = ws; ws += M * 256;
  float* proj1   = ws; ws += M * 64;
  float* s_src   = ws; ws += M * 8;
  float* s_trg   = ws; ws += M * 8;
  float* h1      = ws; ws += M * 64;
  float* m1      = ws; ws += 64;
  float* pooled  = ws; ws += 64 * 256;

  dim3 thr(256);

  // Stage A: bf16x2-split MFMA gates GEMM (K=300, N=1024)
  gemm_gates_mfma<<<dim3(MQ / 128, 1024 / 128), thr, 0, stream>>>(emb, ids, Wih_f, b_f, Wih_b, b_b, gates);

  // Stage B: BiLSTM recurrence (full-asm, uniform-LDS-broadcast matvec)
  lstm_kernel<<<128, 512, 0, stream>>>(ws_base, Whh_f, Whh_b, h_seq);

  // Stage C: GAT layer 1
  gemm_awt<<<dim3(MQ / BM, 1), thr, 0, stream>>>(h_seq, nullptr, g1_W, nullptr, proj1, MQ, 64, 256);
  srctrg_kernel<<<MQ / 256, thr, 0, stream>>>(proj1, g1_src, g1_trg, s_src, s_trg);
  gat1max_kernel<<<Bq, thr, 0, stream>>>(s_src, s_trg, m1);
  gat1_agg_kernel<<<Bq * 8, thr, 0, stream>>>(s_src, s_trg, proj1, m1, g1_b, h1);

  // Stage D: GAT layer 2 attention -> context attention -> softmax -> pooling
  gat2_att_pool_kernel<<<Bq, thr, 0, stream>>>(h1, g2_W, g2_src, g2_trg, ctx, h_seq, att_out, pooled);

  // Stage E: classifier head
  head_kernel<<<64, thr, 0, stream>>>(pooled, lin_W, lin_b, out_W, out_b, logits);
}